// Round 5
// baseline (203.414 us; speedup 1.0000x reference)
//
#include <hip/hip_runtime.h>

#define NNODES 32768
#define NEDGES 524288
#define KCL 64
#define CPG 16   // histogram chunks per graph (4096 edges each)

typedef _Float16 half8v __attribute__((ext_vector_type(8)));
typedef _Float16 half4v __attribute__((ext_vector_type(4)));
typedef float floatx4 __attribute__((ext_vector_type(4)));

// fp16 transposed weight buffer layout (element offsets into wt16):
#define WT1_OFF   0       // W1  [128x128] -> [n*128+k]  (unused; layout stability)
#define WT2_OFF   16384   // W2  [128x128]
#define WTA1_OFF  32768   // Wa1 [128x128]
#define WTA2_OFF  49152   // Wa2 [128x64]  -> [n*128+k], n<64
#define WTO_OFF   57344   // Wo  [128x128]
#define WT_TOTAL  73728

__device__ __forceinline__ float wave_sum(float v) {
#pragma unroll
  for (int off = 32; off > 0; off >>= 1) v += __shfl_xor(v, off, 64);
  return v;
}

// ---------------- fused: per-chunk LDS histogram + weight prep (blocks 0..127)
// ----------------        ∥ layer-1 GEMM h16A = fp16(x @ W1), UNSCALED (blocks 128..383)
__global__ __launch_bounds__(256) void histgemm1_kernel(const int* __restrict__ src, const int* __restrict__ dst,
                                                        int* __restrict__ pIn,
                                                        const float* __restrict__ W1, const float* __restrict__ W2,
                                                        const float* __restrict__ Wa1, const float* __restrict__ Wa2,
                                                        const float* __restrict__ Wo, _Float16* __restrict__ wt16,
                                                        const float* __restrict__ x, _Float16* __restrict__ h16A,
                                                        float* __restrict__ out) {
  __shared__ _Float16 WT[128][136];
  const int t = threadIdx.x;
  if (blockIdx.x < 128) {
    int* hIn = reinterpret_cast<int*>(&WT[0][0]);
    const int g = blockIdx.x & 7;
    const int chunk = blockIdx.x >> 3;
    const int ebase = (g << 16) + (chunk << 12);
    const int nbase = g << 12;
    if (blockIdx.x == 0 && t < 2) out[98816 + t] = 0.f;  // zero loss accumulators
    for (int i = t; i < 4096; i += 256) hIn[i] = 0;
    __syncthreads();
    {
      int tg = blockIdx.x * 256 + t;
#pragma unroll
      for (int i = 0; i < 3; i++) {
        int id = tg + i * 32768;
        if (id < WT_TOTAL) {
          const float* W; int base, BN;
          if (id < 16384)      { W = W1;  base = WT1_OFF;  BN = 128; }
          else if (id < 32768) { W = W2;  base = WT2_OFF;  BN = 128; }
          else if (id < 49152) { W = Wa1; base = WTA1_OFF; BN = 128; }
          else if (id < 57344) { W = Wa2; base = WTA2_OFF; BN = 64; }
          else                 { W = Wo;  base = WTO_OFF;  BN = 128; }
          int m = id - base;
          int k = m / BN, n = m % BN;
          wt16[base + n * 128 + k] = (_Float16)W[m];
        }
      }
    }
    const int4* dst4 = reinterpret_cast<const int4*>(dst + ebase);
#pragma unroll
    for (int i = 0; i < 4; ++i) {
      int4 d = dst4[i * 256 + t];
      atomicAdd(&hIn[d.x - nbase], 1);
      atomicAdd(&hIn[d.y - nbase], 1);
      atomicAdd(&hIn[d.z - nbase], 1);
      atomicAdd(&hIn[d.w - nbase], 1);
    }
    __syncthreads();
    int* dIn = pIn + ((size_t)(g * CPG + chunk) << 12);
    for (int i = t; i < 4096; i += 256) dIn[i] = hIn[i];
  } else {
    const int bid = blockIdx.x - 128;
    const int lane = t & 63;
    const int quad = lane >> 4, l16 = lane & 15;
    const long rowbase = (long)(bid & 7) * 4096 + (long)(bid >> 3) * 128 + (t >> 6) * 32;
    half8v af[2][4];
#pragma unroll
    for (int rt = 0; rt < 2; rt++)
#pragma unroll
      for (int kt = 0; kt < 4; kt++) {
        const float* p = x + (rowbase + rt * 16 + l16) * 128 + kt * 32 + quad * 8;
        float4 p0 = *reinterpret_cast<const float4*>(p);
        float4 p1 = *reinterpret_cast<const float4*>(p + 4);
        half8v h = {(_Float16)p0.x, (_Float16)p0.y, (_Float16)p0.z, (_Float16)p0.w,
                    (_Float16)p1.x, (_Float16)p1.y, (_Float16)p1.z, (_Float16)p1.w};
        af[rt][kt] = h;
      }
#pragma unroll
    for (int i = 0; i < 16; i++) {
      int idx = i * 256 + t;           // 0..4095
      int k = idx >> 5, n4 = (idx & 31) << 2;
      float4 wv = *reinterpret_cast<const float4*>(W1 + k * 128 + n4);
      WT[n4 + 0][k] = (_Float16)wv.x;
      WT[n4 + 1][k] = (_Float16)wv.y;
      WT[n4 + 2][k] = (_Float16)wv.z;
      WT[n4 + 3][k] = (_Float16)wv.w;
    }
    __syncthreads();
    floatx4 acc[2][8];
#pragma unroll
    for (int rt = 0; rt < 2; rt++)
#pragma unroll
      for (int ct = 0; ct < 8; ct++) acc[rt][ct] = {0.f, 0.f, 0.f, 0.f};
#pragma unroll
    for (int kt = 0; kt < 4; kt++) {
      half8v bf[8];
#pragma unroll
      for (int ct = 0; ct < 8; ct++)
        bf[ct] = *reinterpret_cast<const half8v*>(&WT[ct * 16 + l16][kt * 32 + quad * 8]);
#pragma unroll
      for (int rt = 0; rt < 2; rt++)
#pragma unroll
        for (int ct = 0; ct < 8; ct++)
          acc[rt][ct] = __builtin_amdgcn_mfma_f32_16x16x32_f16(af[rt][kt], bf[ct], acc[rt][ct], 0, 0, 0);
    }
#pragma unroll
    for (int rt = 0; rt < 2; rt++) {
#pragma unroll
      for (int r = 0; r < 4; r++) {
        long row = rowbase + rt * 16 + quad * 4 + r;
#pragma unroll
        for (int ct = 0; ct < 8; ct++)
          h16A[row * 128 + ct * 16 + l16] = (_Float16)acc[rt][ct][r];
      }
    }
  }
}

// ---------------- per-graph scan: offs, dis, cursor init (cur = offs) ----------------
// Single int4 streaming pass over pIn; no per-chunk cbase (scatter uses global atomics).
__global__ __launch_bounds__(1024) void scan2_kernel(const int* __restrict__ pIn, int* __restrict__ offs,
                                                     int* __restrict__ cur, float* __restrict__ dis) {
  __shared__ int part[1024];
  const int t = threadIdx.x;
  const int g = blockIdx.x;
  int4 tot = {0, 0, 0, 0};
#pragma unroll
  for (int c = 0; c < CPG; ++c) {
    int4 cc = *reinterpret_cast<const int4*>(pIn + (((size_t)(g * CPG + c)) << 12) + t * 4);
    tot.x += cc.x; tot.y += cc.y; tot.z += cc.z; tot.w += cc.w;
  }
  part[t] = tot.x + tot.y + tot.z + tot.w;
  __syncthreads();
  for (int off = 1; off < 1024; off <<= 1) {
    int add = (t >= off) ? part[t - off] : 0;
    __syncthreads();
    part[t] += add;
    __syncthreads();
  }
  const int run0 = (g << 16) + ((t == 0) ? 0 : part[t - 1]);
  int4 offv = {run0, run0 + tot.x, run0 + tot.x + tot.y, run0 + tot.x + tot.y + tot.z};
  *reinterpret_cast<int4*>(offs + (g << 12) + t * 4) = offv;
  *reinterpret_cast<int4*>(cur + (g << 12) + t * 4) = offv;
  float4 dv = {rsqrtf((float)tot.x + 1.0f), rsqrtf((float)tot.y + 1.0f),
               rsqrtf((float)tot.z + 1.0f), rsqrtf((float)tot.w + 1.0f)};
  *reinterpret_cast<float4*>(dis + (g << 12) + t * 4) = dv;
  if (g == 0 && t == 0) offs[NNODES] = NEDGES;
}

// ---------------- scatter via global atomic cursors (no LDS staging, no cbase) ----------------
// Edge order within a node's list is nondeterministic; aggregation is fp32 so reorder
// noise is ~1e-6 absolute — far under tolerance.
__global__ __launch_bounds__(256) void scatter2_kernel(const int* __restrict__ src, const int* __restrict__ dst,
                                                       int* __restrict__ cur, int* __restrict__ ssrc) {
  const int t = threadIdx.x;
  const int ebase = ((blockIdx.x & 7) << 16) + ((blockIdx.x >> 3) << 12);
  const int4* dst4 = reinterpret_cast<const int4*>(dst + ebase);
  const int4* src4 = reinterpret_cast<const int4*>(src + ebase);
#pragma unroll
  for (int i = 0; i < 4; ++i) {
    int4 d = dst4[i * 256 + t];
    int4 s = src4[i * 256 + t];
    int p0 = atomicAdd(&cur[d.x], 1); ssrc[p0] = s.x;
    int p1 = atomicAdd(&cur[d.y], 1); ssrc[p1] = s.y;
    int p2 = atomicAdd(&cur[d.z], 1); ssrc[p2] = s.z;
    int p3 = atomicAdd(&cur[d.w], 1); ssrc[p3] = s.w;
  }
}

// ---------------- MFMA fp16 GEMM: C[M x 128] = A[M x 128] @ W, W pre-transposed fp16 ----------------
template <int ACT, int BIAS, int SCALE, int AFP32>
__global__ __launch_bounds__(256) void mgemm_kernel(const void* __restrict__ Ain, const _Float16* __restrict__ WT16,
                                                    const float* __restrict__ bias, const float* __restrict__ rowscale,
                                                    _Float16* __restrict__ Cout) {
  __shared__ _Float16 WT[128][136];
  const int t = threadIdx.x;
  const int lane = t & 63;
  const int quad = lane >> 4, l16 = lane & 15;
  const long rowbase = (long)(blockIdx.x & 7) * 4096 + (long)(blockIdx.x >> 3) * 128 + (t >> 6) * 32;
  half8v af[2][4];
#pragma unroll
  for (int rt = 0; rt < 2; rt++)
#pragma unroll
    for (int kt = 0; kt < 4; kt++) {
      if (AFP32) {
        const float* A32 = (const float*)Ain;
        const float* p = A32 + (rowbase + rt * 16 + l16) * 128 + kt * 32 + quad * 8;
        float4 p0 = *reinterpret_cast<const float4*>(p);
        float4 p1 = *reinterpret_cast<const float4*>(p + 4);
        half8v h = {(_Float16)p0.x, (_Float16)p0.y, (_Float16)p0.z, (_Float16)p0.w,
                    (_Float16)p1.x, (_Float16)p1.y, (_Float16)p1.z, (_Float16)p1.w};
        af[rt][kt] = h;
      } else {
        const _Float16* A16 = (const _Float16*)Ain;
        af[rt][kt] = *reinterpret_cast<const half8v*>(A16 + (rowbase + rt * 16 + l16) * 128 + kt * 32 + quad * 8);
      }
    }
#pragma unroll
  for (int i = 0; i < 8; i++) {
    int idx = i * 256 + t;
    int n = idx >> 4, k8 = (idx & 15) << 3;
    *reinterpret_cast<half8v*>(&WT[n][k8]) = *reinterpret_cast<const half8v*>(&WT16[n * 128 + k8]);
  }
  __syncthreads();
  floatx4 acc[2][8];
#pragma unroll
  for (int rt = 0; rt < 2; rt++)
#pragma unroll
    for (int ct = 0; ct < 8; ct++) acc[rt][ct] = {0.f, 0.f, 0.f, 0.f};
#pragma unroll
  for (int kt = 0; kt < 4; kt++) {
    half8v bf[8];
#pragma unroll
    for (int ct = 0; ct < 8; ct++)
      bf[ct] = *reinterpret_cast<const half8v*>(&WT[ct * 16 + l16][kt * 32 + quad * 8]);
#pragma unroll
    for (int rt = 0; rt < 2; rt++)
#pragma unroll
      for (int ct = 0; ct < 8; ct++)
        acc[rt][ct] = __builtin_amdgcn_mfma_f32_16x16x32_f16(af[rt][kt], bf[ct], acc[rt][ct], 0, 0, 0);
  }
#pragma unroll
  for (int rt = 0; rt < 2; rt++) {
#pragma unroll
    for (int r = 0; r < 4; r++) {
      long row = rowbase + rt * 16 + quad * 4 + r;
      float sc = SCALE ? rowscale[row] : 1.f;
#pragma unroll
      for (int ct = 0; ct < 8; ct++) {
        float v = acc[rt][ct][r];
        if (SCALE) v *= sc;
        if (BIAS) v += bias[ct * 16 + l16];
        if (ACT == 1) v = fmaxf(v, 0.f);
        Cout[row * 128 + ct * 16 + l16] = (_Float16)v;
      }
    }
  }
}

// ---------------- fused assignment MLP: 512 blocks x 64 rows ----------------
__global__ __launch_bounds__(256) void mlp_kernel(const _Float16* __restrict__ h2, const _Float16* __restrict__ wta1,
                                                  const _Float16* __restrict__ wta2, const float* __restrict__ ba1,
                                                  const float* __restrict__ ba2, _Float16* __restrict__ sh) {
  __shared__ _Float16 WT1[128][136];
  __shared__ _Float16 Z[64][136];
  const int t = threadIdx.x;
  const int lane = t & 63;
  const int quad = lane >> 4, l16 = lane & 15;
  const int w = t >> 6;
  const long rowbase = (long)(blockIdx.x & 7) * 4096 + (long)(blockIdx.x >> 3) * 64 + w * 16;
  half8v af[4];
#pragma unroll
  for (int kt = 0; kt < 4; kt++)
    af[kt] = *reinterpret_cast<const half8v*>(h2 + (rowbase + l16) * 128 + kt * 32 + quad * 8);
#pragma unroll
  for (int i = 0; i < 8; i++) {
    int idx = i * 256 + t;
    int n = idx >> 4, k8 = (idx & 15) << 3;
    *reinterpret_cast<half8v*>(&WT1[n][k8]) = *reinterpret_cast<const half8v*>(&wta1[n * 128 + k8]);
  }
  __syncthreads();
  {
    floatx4 acc[8];
#pragma unroll
    for (int ct = 0; ct < 8; ct++) acc[ct] = {0.f, 0.f, 0.f, 0.f};
#pragma unroll
    for (int kt = 0; kt < 4; kt++) {
#pragma unroll
      for (int ct = 0; ct < 8; ct++) {
        half8v bf = *reinterpret_cast<const half8v*>(&WT1[ct * 16 + l16][kt * 32 + quad * 8]);
        acc[ct] = __builtin_amdgcn_mfma_f32_16x16x32_f16(af[kt], bf, acc[ct], 0, 0, 0);
      }
    }
#pragma unroll
    for (int r = 0; r < 4; r++) {
      int lrow = w * 16 + quad * 4 + r;
#pragma unroll
      for (int ct = 0; ct < 8; ct++) {
        float zx = acc[ct][r] + ba1[ct * 16 + l16];
        float ex = __expf(2.0f * zx);
        float v = 1.0f - 2.0f * __builtin_amdgcn_rcpf(ex + 1.0f);
        Z[lrow][ct * 16 + l16] = (_Float16)v;
      }
    }
  }
  __syncthreads();
#pragma unroll
  for (int i = 0; i < 4; i++) {
    int idx = i * 256 + t;
    int n = idx >> 4, k8 = (idx & 15) << 3;
    *reinterpret_cast<half8v*>(&WT1[n][k8]) = *reinterpret_cast<const half8v*>(&wta2[n * 128 + k8]);
  }
  half8v af2[4];
#pragma unroll
  for (int kt = 0; kt < 4; kt++)
    af2[kt] = *reinterpret_cast<const half8v*>(&Z[w * 16 + l16][kt * 32 + quad * 8]);
  __syncthreads();
  floatx4 acc2[4];
#pragma unroll
  for (int ct = 0; ct < 4; ct++) acc2[ct] = {0.f, 0.f, 0.f, 0.f};
#pragma unroll
  for (int kt = 0; kt < 4; kt++) {
#pragma unroll
    for (int ct = 0; ct < 4; ct++) {
      half8v bf = *reinterpret_cast<const half8v*>(&WT1[ct * 16 + l16][kt * 32 + quad * 8]);
      acc2[ct] = __builtin_amdgcn_mfma_f32_16x16x32_f16(af2[kt], bf, acc2[ct], 0, 0, 0);
    }
  }
#pragma unroll
  for (int r = 0; r < 4; r++) {
    long row = rowbase + quad * 4 + r;
    float v[4];
#pragma unroll
    for (int ct = 0; ct < 4; ct++) v[ct] = acc2[ct][r] + ba2[ct * 16 + l16];
    float m = fmaxf(fmaxf(v[0], v[1]), fmaxf(v[2], v[3]));
#pragma unroll
    for (int off = 1; off <= 8; off <<= 1) m = fmaxf(m, __shfl_xor(m, off, 64));
    float se = 0.f;
#pragma unroll
    for (int ct = 0; ct < 4; ct++) { v[ct] = __expf(v[ct] - m); se += v[ct]; }
#pragma unroll
    for (int off = 1; off <= 8; off <<= 1) se += __shfl_xor(se, off, 64);
    float inv = 1.0f / se;
#pragma unroll
    for (int ct = 0; ct < 4; ct++) v[ct] *= inv;
    float m2 = fmaxf(fmaxf(v[0], v[1]), fmaxf(v[2], v[3]));
#pragma unroll
    for (int off = 1; off <= 8; off <<= 1) m2 = fmaxf(m2, __shfl_xor(m2, off, 64));
    float se2 = 0.f;
#pragma unroll
    for (int ct = 0; ct < 4; ct++) { v[ct] = __expf(v[ct] - m2); se2 += v[ct]; }
#pragma unroll
    for (int off = 1; off <= 8; off <<= 1) se2 += __shfl_xor(se2, off, 64);
    float inv2 = 1.0f / se2;
#pragma unroll
    for (int ct = 0; ct < 4; ct++) sh[row * 64 + ct * 16 + l16] = (_Float16)(v[ct] * inv2);
  }
}

// ---------------- GCN aggregation: 16-stride main + one masked 16-tail ----------------
template <int RELU, int DISSRC>
__global__ __launch_bounds__(256) void aggregate_kernel(const _Float16* __restrict__ hs, const float* __restrict__ dis,
                                                        const int* __restrict__ offs, const int* __restrict__ ssrc,
                                                        const float* __restrict__ bias, _Float16* __restrict__ outh) {
  const int lane = threadIdx.x & 63;
  const int b = blockIdx.x;
  const int node = ((b & 7) << 12) + ((b >> 3) << 2) + (threadIdx.x >> 6);
  const int q = lane >> 4;
  const int fl = (lane & 15) * 8;
  const int e0 = offs[node], e1 = offs[node + 1];
  const float dn = dis[node];
  float fa[8];
#pragma unroll
  for (int j = 0; j < 8; j++) fa[j] = 0.f;
  int e = e0;
  for (; e + 16 <= e1; e += 16) {
    int s0 = ssrc[e + q];
    int s1 = ssrc[e + 4 + q];
    int s2 = ssrc[e + 8 + q];
    int s3 = ssrc[e + 12 + q];
    float d0 = 1.f, d1 = 1.f, d2 = 1.f, d3 = 1.f;
    if (DISSRC) { d0 = dis[s0]; d1 = dis[s1]; d2 = dis[s2]; d3 = dis[s3]; }
    half8v v0 = *reinterpret_cast<const half8v*>(hs + (size_t)s0 * 128 + fl);
    half8v v1 = *reinterpret_cast<const half8v*>(hs + (size_t)s1 * 128 + fl);
    half8v v2 = *reinterpret_cast<const half8v*>(hs + (size_t)s2 * 128 + fl);
    half8v v3 = *reinterpret_cast<const half8v*>(hs + (size_t)s3 * 128 + fl);
#pragma unroll
    for (int j = 0; j < 8; j++) {
      if (DISSRC) {
        fa[j] = fmaf(d0, (float)v0[j], fa[j]);
        fa[j] = fmaf(d1, (float)v1[j], fa[j]);
        fa[j] = fmaf(d2, (float)v2[j], fa[j]);
        fa[j] = fmaf(d3, (float)v3[j], fa[j]);
      } else {
        fa[j] += (float)v0[j] + (float)v1[j] + (float)v2[j] + (float)v3[j];
      }
    }
  }
  if (e < e1) {
    int last = e1 - 1;
    int s[4]; bool m[4];
#pragma unroll
    for (int jj = 0; jj < 4; jj++) {
      int idx = e + jj * 4 + q;
      m[jj] = idx < e1;
      int sv = ssrc[idx < last ? idx : last];
      s[jj] = m[jj] ? sv : node;
    }
#pragma unroll
    for (int jj = 0; jj < 4; jj++) {
      half8v v = *reinterpret_cast<const half8v*>(hs + (size_t)s[jj] * 128 + fl);
      float ds = DISSRC ? dis[s[jj]] : 1.f;
      if (m[jj]) {
#pragma unroll
        for (int j = 0; j < 8; j++) {
          if (DISSRC) fa[j] = fmaf(ds, (float)v[j], fa[j]);
          else fa[j] += (float)v[j];
        }
      }
    }
  }
#pragma unroll
  for (int j = 0; j < 8; j++) {
    fa[j] += __shfl_xor(fa[j], 16, 64);
    fa[j] += __shfl_xor(fa[j], 32, 64);
  }
  if (q == 0) {
    half8v self = *reinterpret_cast<const half8v*>(hs + (size_t)node * 128 + fl);
    float4 b0 = *reinterpret_cast<const float4*>(bias + fl);
    float4 b1 = *reinterpret_cast<const float4*>(bias + fl + 4);
    float bb[8] = {b0.x, b0.y, b0.z, b0.w, b1.x, b1.y, b1.z, b1.w};
    half8v r;
#pragma unroll
    for (int j = 0; j < 8; j++) {
      float acc = fa[j];
      if (DISSRC) acc = fmaf(dn, (float)self[j], acc);      // self row unscaled: dis_d * h_d
      else acc += (float)self[j];                            // self row pre-scaled by dis_d
      float v = fmaf(acc, dn, bb[j]);
      if (RELU) v = fmaxf(v, 0.f);
      r[j] = (_Float16)v;
    }
    *reinterpret_cast<half8v*>(outh + (size_t)node * 128 + fl) = r;
  }
}

// ---------------- G + den: 16-stride main + one masked 16-tail ----------------
__global__ __launch_bounds__(256) void gather_kernel(const _Float16* __restrict__ sh, const int* __restrict__ offs,
                                                     const int* __restrict__ ssrc, _Float16* __restrict__ Gh,
                                                     float* __restrict__ dnp) {
  const int lane = threadIdx.x & 63;
  const int b = blockIdx.x;
  const int node = ((b & 7) << 12) + ((b >> 3) << 2) + (threadIdx.x >> 6);
  const int q = lane >> 3;
  const int fl = (lane & 7) * 8;
  const int e0 = offs[node], e1 = offs[node + 1];
  float fa[8];
  float sq = 0.f;
#pragma unroll
  for (int j = 0; j < 8; j++) fa[j] = 0.f;
  int e = e0;
  for (; e + 16 <= e1; e += 16) {
    int s0 = ssrc[e + q];
    int s1 = ssrc[e + 8 + q];
    half8v v0 = *reinterpret_cast<const half8v*>(sh + (size_t)s0 * 64 + fl);
    half8v v1 = *reinterpret_cast<const half8v*>(sh + (size_t)s1 * 64 + fl);
#pragma unroll
    for (int j = 0; j < 8; j++) {
      float f0 = (float)v0[j], f1 = (float)v1[j];
      fa[j] += f0 + f1;
      sq = fmaf(f0, f0, sq);
      sq = fmaf(f1, f1, sq);
    }
  }
  if (e < e1) {
    int last = e1 - 1;
    int i0 = e + q, i1 = e + 8 + q;
    bool m0 = i0 < e1, m1 = i1 < e1;
    int sv0 = ssrc[i0 < last ? i0 : last];
    int sv1 = ssrc[i1 < last ? i1 : last];
    int s0 = m0 ? sv0 : node;
    int s1 = m1 ? sv1 : node;
    half8v v0 = *reinterpret_cast<const half8v*>(sh + (size_t)s0 * 64 + fl);
    half8v v1 = *reinterpret_cast<const half8v*>(sh + (size_t)s1 * 64 + fl);
#pragma unroll
    for (int j = 0; j < 8; j++) {
      float f0 = m0 ? (float)v0[j] : 0.f;
      float f1 = m1 ? (float)v1[j] : 0.f;
      fa[j] += f0 + f1;
      sq = fmaf(f0, f0, sq);
      sq = fmaf(f1, f1, sq);
    }
  }
#pragma unroll
  for (int j = 0; j < 8; j++) {
    fa[j] += __shfl_xor(fa[j], 8, 64);
    fa[j] += __shfl_xor(fa[j], 16, 64);
    fa[j] += __shfl_xor(fa[j], 32, 64);
  }
  float den = wave_sum(sq);
  if (lane == 0) dnp[node] = den;
  if (q == 0) {
    half8v r;
#pragma unroll
    for (int j = 0; j < 8; j++) r[j] = (_Float16)fa[j];
    *reinterpret_cast<half8v*>(Gh + (size_t)node * 64 + fl) = r;
  }
}

// ---------------- rank reduction via MFMA: C[64 x 256] = s_chunk^T [G | s | h2] ----------------
__global__ __launch_bounds__(512) void atb_kernel(const _Float16* __restrict__ sh, const _Float16* __restrict__ Gh,
                                                  const _Float16* __restrict__ h2, float* __restrict__ pF) {
  __shared__ _Float16 XsT[64][136];   // [cluster m][node k 0..127]
  __shared__ _Float16 YsT[256][40];   // [col n][node k 0..31 within kt]
  const int t = threadIdx.x;
  const int g = blockIdx.x & 7, chunk = blockIdx.x >> 3;
  const int n0 = g * 4096 + chunk * 128;
  const int lane = t & 63;
  const int w = t >> 6;
  const int mtile = w & 3;
  const int nhalf = w >> 2;
  const int quad = lane >> 4, l16 = lane & 15;

#pragma unroll
  for (int i = 0; i < 4; i++) {
    int slot = i * 512 + t;
    int k = slot >> 4, c4 = (slot & 15) * 4;
    half4v v = *reinterpret_cast<const half4v*>(&sh[(size_t)(n0 + k) * 64 + c4]);
#pragma unroll
    for (int j = 0; j < 4; j++) XsT[c4 + j][k] = v[j];
  }

  floatx4 acc[8];
#pragma unroll
  for (int nt = 0; nt < 8; nt++) acc[nt] = {0.f, 0.f, 0.f, 0.f};

  for (int kt = 0; kt < 4; ++kt) {
    const int nb = n0 + kt * 32;
    __syncthreads();
#pragma unroll
    for (int i = 0; i < 4; i++) {
      int slot = i * 512 + t;
      int cg = slot & 15, k = (slot >> 4) & 31, ch = slot >> 9;
      int c = ch * 64 + cg * 4;
      half4v v;
      if (c < 64)       v = *reinterpret_cast<const half4v*>(&Gh[(size_t)(nb + k) * 64 + c]);
      else if (c < 128) v = *reinterpret_cast<const half4v*>(&sh[(size_t)(nb + k) * 64 + (c - 64)]);
      else              v = *reinterpret_cast<const half4v*>(&h2[(size_t)(nb + k) * 128 + (c - 128)]);
#pragma unroll
      for (int j = 0; j < 4; j++) YsT[c + j][k] = v[j];
    }
    __syncthreads();
    half8v af = *reinterpret_cast<const half8v*>(&XsT[mtile * 16 + l16][kt * 32 + quad * 8]);
#pragma unroll
    for (int nt = 0; nt < 8; nt++) {
      half8v bf = *reinterpret_cast<const half8v*>(&YsT[(nhalf * 8 + nt) * 16 + l16][quad * 8]);
      acc[nt] = __builtin_amdgcn_mfma_f32_16x16x32_f16(af, bf, acc[nt], 0, 0, 0);
    }
  }
  float* dst = pF + (size_t)blockIdx.x * 16384;
#pragma unroll
  for (int nt = 0; nt < 8; nt++) {
#pragma unroll
    for (int r = 0; r < 4; r++) {
      dst[(mtile * 16 + quad * 4 + r) * 256 + (nhalf * 8 + nt) * 16 + l16] = acc[nt][r];
    }
  }
}

// ---------------- merge 32 partials/graph -> oadj, ssb, outp16 ----------------
__global__ __launch_bounds__(256) void merge_kernel(const float* __restrict__ pF, float* __restrict__ oadj,
                                                    float* __restrict__ ssb, _Float16* __restrict__ outp16) {
  int g = blockIdx.x & 7;
  int o4 = (blockIdx.x >> 3) * 256 + threadIdx.x;
  float sx = 0.f, sy = 0.f, sz = 0.f, sw = 0.f;
#pragma unroll
  for (int q = 0; q < 32; ++q) {
    float4 v = *reinterpret_cast<const float4*>(pF + (size_t)(q * 8 + g) * 16384 + o4 * 4);
    sx += v.x; sy += v.y; sz += v.z; sw += v.w;
  }
  int row = o4 >> 6;
  int c = (o4 & 63) * 4;
  if (c < 64) {
    float4 o = {sx, sy, sz, sw};
    *reinterpret_cast<float4*>(&oadj[g * 4096 + row * 64 + c]) = o;
  } else if (c < 128) {
    float4 o = {sx, sy, sz, sw};
    *reinterpret_cast<float4*>(&ssb[g * 4096 + row * 64 + (c - 64)]) = o;
  } else {
    half4v h = {(_Float16)sx, (_Float16)sy, (_Float16)sz, (_Float16)sw};
    *reinterpret_cast<half4v*>(&outp16[g * 8192 + row * 128 + (c - 128)]) = h;
  }
}

// ---------------- epilogue2: losses + adj-norm + pooled MFMA GEMM (8 blocks) ----------------
__global__ __launch_bounds__(256) void epilogue2_kernel(const float* __restrict__ oadj, const float* __restrict__ ssb,
                                                        const _Float16* __restrict__ outp16, const _Float16* __restrict__ wto,
                                                        const float* __restrict__ bo, const float* __restrict__ dn,
                                                        float* __restrict__ out) {
  __shared__ _Float16 outpS[64][136];
  __shared__ _Float16 WoT[128][136];
  __shared__ float red[256];
  __shared__ float rowsum[64];
  __shared__ float dw[4], w1[4], w2[4], w3[4];
  const int g = blockIdx.x, t = threadIdx.x;

#pragma unroll
  for (int i = 0; i < 8; i++) {
    int idx = i * 256 + t;
    int n = idx >> 4, k8 = (idx & 15) << 3;
    *reinterpret_cast<half8v*>(&WoT[n][k8]) = *reinterpret_cast<const half8v*>(&wto[n * 128 + k8]);
  }
#pragma unroll
  for (int i = 0; i < 4; i++) {
    int idx = i * 256 + t;
    int orow = idx >> 4, c8 = (idx & 15) * 8;
    half8v v = *reinterpret_cast<const half8v*>(&outp16[g * 8192 + orow * 128 + c8]);
    *reinterpret_cast<half8v*>(&outpS[orow][c8]) = v;
  }

  const int row = t >> 2, p = t & 3;
  float Areg[16];
  float trs_p = 0.f, ssq_p = 0.f;
#pragma unroll
  for (int c4 = 0; c4 < 4; c4++) {
    float4 a = *reinterpret_cast<const float4*>(&oadj[g * 4096 + row * 64 + p * 16 + c4 * 4]);
    Areg[c4 * 4 + 0] = a.x; Areg[c4 * 4 + 1] = a.y; Areg[c4 * 4 + 2] = a.z; Areg[c4 * 4 + 3] = a.w;
    float4 s = *reinterpret_cast<const float4*>(&ssb[g * 4096 + row * 64 + p * 16 + c4 * 4]);
    float vv[4] = {s.x, s.y, s.z, s.w};
#pragma unroll
    for (int jj = 0; jj < 4; jj++) {
      ssq_p += vv[jj] * vv[jj];
      int col = p * 16 + c4 * 4 + jj;
      if (col == row) trs_p += vv[jj];
    }
  }
  float da = 0.f;
#pragma unroll
  for (int i = 0; i < 16; i++) da += dn[g * 4096 + i * 256 + t];
  float dws = wave_sum(da);
  if ((t & 63) == 0) dw[t >> 6] = dws;

  float rs = 0.f, tra = 0.f;
#pragma unroll
  for (int c = 0; c < 16; c++) {
    int j = p * 16 + c;
    if (j == row) tra += Areg[c];
    else rs += Areg[c];
  }
  red[t] = rs;
  __syncthreads();
  if (p == 0) rowsum[row] = red[t] + red[t + 1] + red[t + 2] + red[t + 3];
  float v1 = wave_sum(tra), v2 = wave_sum(trs_p), v3 = wave_sum(ssq_p);
  if ((t & 63) == 0) { int w = t >> 6; w1[w] = v1; w2[w] = v2; w3[w] = v3; }
  __syncthreads();
  if (t == 0) {
    float TRA = w1[0] + w1[1] + w1[2] + w1[3];
    float TRS = w2[0] + w2[1] + w2[2] + w2[3];
    float SSQ = w3[0] + w3[1] + w3[2] + w3[3];
    float DEN = dw[0] + dw[1] + dw[2] + dw[3];
    atomicAdd(&out[98816], -(TRA / DEN) * 0.125f);
    float ssn = sqrtf(SSQ);
    atomicAdd(&out[98817], sqrtf(2.0f - TRS / (4.0f * ssn)) * 0.125f);
  }
  float di = sqrtf(rowsum[row]) + 1e-15f;
#pragma unroll
  for (int c = 0; c < 16; c++) {
    int j = p * 16 + c;
    float v = (j == row) ? 0.f : Areg[c];
    float dj = sqrtf(rowsum[j]) + 1e-15f;
    out[65536 + g * 4096 + row * 64 + j] = v / (di * dj);
  }
  if (t < 64) out[98304 + g * 64 + t] = (float)g;

  const int lane = t & 63;
  const int quad = lane >> 4, l16 = lane & 15;
  const int w = t >> 6;
  floatx4 acc[8];
#pragma unroll
  for (int ct = 0; ct < 8; ct++) acc[ct] = {0.f, 0.f, 0.f, 0.f};
#pragma unroll
  for (int kt = 0; kt < 4; kt++) {
    half8v af = *reinterpret_cast<const half8v*>(&outpS[w * 16 + l16][kt * 32 + quad * 8]);
#pragma unroll
    for (int ct = 0; ct < 8; ct++) {
      half8v bf = *reinterpret_cast<const half8v*>(&WoT[ct * 16 + l16][kt * 32 + quad * 8]);
      acc[ct] = __builtin_amdgcn_mfma_f32_16x16x32_f16(af, bf, acc[ct], 0, 0, 0);
    }
  }
#pragma unroll
  for (int r = 0; r < 4; r++) {
    int orow = w * 16 + quad * 4 + r;
#pragma unroll
    for (int ct = 0; ct < 8; ct++) {
      int col = ct * 16 + l16;
      float v = fmaxf(acc[ct][r] + bo[col], 0.f);
      out[(g * 64 + orow) * 128 + col] = v;
    }
  }
}

extern "C" void kernel_launch(void* const* d_in, const int* in_sizes, int n_in,
                              void* d_out, int out_size, void* d_ws, size_t ws_size,
                              hipStream_t stream) {
  const float* x   = (const float*)d_in[0];
  const int*   ei  = (const int*)d_in[1];
  const float* W1  = (const float*)d_in[3];
  const float* b1  = (const float*)d_in[4];
  const float* W2  = (const float*)d_in[5];
  const float* b2  = (const float*)d_in[6];
  const float* Wa1 = (const float*)d_in[7];
  const float* ba1 = (const float*)d_in[8];
  const float* Wa2 = (const float*)d_in[9];
  const float* ba2 = (const float*)d_in[10];
  const float* Wo  = (const float*)d_in[11];
  const float* bo  = (const float*)d_in[12];
  const int* src = ei;
  const int* dst = ei + NEDGES;
  float* out = (float*)d_out;

  char* ws = (char*)d_ws;
  size_t o = 0;
  auto alloc = [&](size_t bytes) -> void* {
    void* p = ws + o;
    o += (bytes + 255) & ~(size_t)255;
    return p;
  };
  _Float16* h16A = (_Float16*)alloc((size_t)NNODES * 128 * 2);
  _Float16* h16B = (_Float16*)alloc((size_t)NNODES * 128 * 2);
  _Float16* h16C = (_Float16*)alloc((size_t)NNODES * 128 * 2);
  _Float16* sh   = (_Float16*)alloc((size_t)NNODES * 64 * 2);
  _Float16* Gh   = (_Float16*)alloc((size_t)NNODES * 64 * 2);
  float* pF    = (float*)alloc((size_t)256 * 16384 * 4);
  float* dis   = (float*)alloc((size_t)NNODES * 4);
  int* offs    = (int*)alloc((size_t)(NNODES + 1) * 4);
  int* ssrc    = (int*)alloc((size_t)NEDGES * 4);
  int* pIn     = (int*)alloc((size_t)8 * CPG * 4096 * 4);
  int* cur     = (int*)alloc((size_t)NNODES * 4);
  float* dn    = (float*)alloc((size_t)NNODES * 4);
  float* oadj  = (float*)alloc(8 * 4096 * 4);
  float* ssb   = (float*)alloc(8 * 4096 * 4);
  _Float16* outp16 = (_Float16*)alloc(8 * 8192 * 2);
  _Float16* wt16   = (_Float16*)alloc((size_t)WT_TOTAL * 2);

  // 1: histogram (blocks 0..127) || layer-1 GEMM (blocks 128..383, unscaled)
  histgemm1_kernel<<<384, 256, 0, stream>>>(src, dst, pIn, W1, W2, Wa1, Wa2, Wo, wt16, x, h16A, out);
  // 2-3: CSR build (scan: offs/dis/cursor-init; scatter: global atomic cursors)
  scan2_kernel<<<8, 1024, 0, stream>>>(pIn, offs, cur, dis);
  scatter2_kernel<<<8 * CPG, 256, 0, stream>>>(src, dst, cur, ssrc);

  // layer 1 aggregate: per-edge dis[src] (deferred producer scale) + dis[dst], bias, relu
  aggregate_kernel<1, 1><<<NNODES / 4, 256, 0, stream>>>(h16A, dis, offs, ssrc, b1, h16B);
  mgemm_kernel<0, 0, 1, 0><<<NNODES / 128, 256, 0, stream>>>(h16B, wt16 + WT2_OFF, nullptr, dis, h16A);
  aggregate_kernel<0, 0><<<NNODES / 4, 256, 0, stream>>>(h16A, dis, offs, ssrc, b2, h16C);

  mlp_kernel<<<NNODES / 64, 256, 0, stream>>>(h16C, wt16 + WTA1_OFF, wt16 + WTA2_OFF, ba1, ba2, sh);

  gather_kernel<<<NNODES / 4, 256, 0, stream>>>(sh, offs, ssrc, Gh, dn);
  atb_kernel<<<256, 512, 0, stream>>>(sh, Gh, h16C, pF);
  merge_kernel<<<128, 256, 0, stream>>>(pF, oadj, ssb, outp16);
  epilogue2_kernel<<<8, 256, 0, stream>>>(oadj, ssb, outp16, wt16 + WTO_OFF, bo, dn, out);
}

// Round 6
// 187.395 us; speedup vs baseline: 1.0855x; 1.0855x over previous
//
#include <hip/hip_runtime.h>

#define NNODES 32768
#define NEDGES 524288
#define KCL 64
#define CPG 16   // histogram chunks per graph (4096 edges each)

typedef _Float16 half8v __attribute__((ext_vector_type(8)));
typedef _Float16 half4v __attribute__((ext_vector_type(4)));
typedef float floatx4 __attribute__((ext_vector_type(4)));

// fp16 transposed weight buffer layout (element offsets into wt16):
#define WT1_OFF   0       // W1  [128x128] -> [n*128+k]  (unused; layout stability)
#define WT2_OFF   16384   // W2  [128x128]
#define WTA1_OFF  32768   // Wa1 [128x128]
#define WTA2_OFF  49152   // Wa2 [128x64]  -> [n*128+k], n<64
#define WTO_OFF   57344   // Wo  [128x128]
#define WT_TOTAL  73728

__device__ __forceinline__ float wave_sum(float v) {
#pragma unroll
  for (int off = 32; off > 0; off >>= 1) v += __shfl_xor(v, off, 64);
  return v;
}

// ---------------- fused: per-chunk LDS histogram + weight prep (blocks 0..127)
// ----------------        ∥ layer-1 GEMM h16A = fp16(x @ W1), UNSCALED (blocks 128..383)
__global__ __launch_bounds__(256) void histgemm1_kernel(const int* __restrict__ src, const int* __restrict__ dst,
                                                        int* __restrict__ pIn,
                                                        const float* __restrict__ W1, const float* __restrict__ W2,
                                                        const float* __restrict__ Wa1, const float* __restrict__ Wa2,
                                                        const float* __restrict__ Wo, _Float16* __restrict__ wt16,
                                                        const float* __restrict__ x, _Float16* __restrict__ h16A,
                                                        float* __restrict__ out) {
  __shared__ alignas(16) _Float16 WT[128][136];
  const int t = threadIdx.x;
  if (blockIdx.x < 128) {
    int* hIn = reinterpret_cast<int*>(&WT[0][0]);
    const int g = blockIdx.x & 7;
    const int chunk = blockIdx.x >> 3;
    const int ebase = (g << 16) + (chunk << 12);
    const int nbase = g << 12;
    if (blockIdx.x == 0 && t < 2) out[98816 + t] = 0.f;  // zero loss accumulators
    {
      int4 z = {0, 0, 0, 0};
      int4* h4 = reinterpret_cast<int4*>(hIn);
#pragma unroll
      for (int i = 0; i < 4; i++) h4[i * 256 + t] = z;
    }
    __syncthreads();
    {
      int tg = blockIdx.x * 256 + t;
#pragma unroll
      for (int i = 0; i < 3; i++) {
        int id = tg + i * 32768;
        if (id < WT_TOTAL) {
          const float* W; int base, BN;
          if (id < 16384)      { W = W1;  base = WT1_OFF;  BN = 128; }
          else if (id < 32768) { W = W2;  base = WT2_OFF;  BN = 128; }
          else if (id < 49152) { W = Wa1; base = WTA1_OFF; BN = 128; }
          else if (id < 57344) { W = Wa2; base = WTA2_OFF; BN = 64; }
          else                 { W = Wo;  base = WTO_OFF;  BN = 128; }
          int m = id - base;
          int k = m / BN, n = m % BN;
          wt16[base + n * 128 + k] = (_Float16)W[m];
        }
      }
    }
    const int4* dst4 = reinterpret_cast<const int4*>(dst + ebase);
#pragma unroll
    for (int i = 0; i < 4; ++i) {
      int4 d = dst4[i * 256 + t];
      atomicAdd(&hIn[d.x - nbase], 1);
      atomicAdd(&hIn[d.y - nbase], 1);
      atomicAdd(&hIn[d.z - nbase], 1);
      atomicAdd(&hIn[d.w - nbase], 1);
    }
    __syncthreads();
    int4* dIn4 = reinterpret_cast<int4*>(pIn + ((size_t)(g * CPG + chunk) << 12));
    const int4* h4 = reinterpret_cast<const int4*>(hIn);
#pragma unroll
    for (int i = 0; i < 4; i++) dIn4[i * 256 + t] = h4[i * 256 + t];
  } else {
    const int bid = blockIdx.x - 128;
    const int lane = t & 63;
    const int quad = lane >> 4, l16 = lane & 15;
    const long rowbase = (long)(bid & 7) * 4096 + (long)(bid >> 3) * 128 + (t >> 6) * 32;
    half8v af[2][4];
#pragma unroll
    for (int rt = 0; rt < 2; rt++)
#pragma unroll
      for (int kt = 0; kt < 4; kt++) {
        const float* p = x + (rowbase + rt * 16 + l16) * 128 + kt * 32 + quad * 8;
        float4 p0 = *reinterpret_cast<const float4*>(p);
        float4 p1 = *reinterpret_cast<const float4*>(p + 4);
        half8v h = {(_Float16)p0.x, (_Float16)p0.y, (_Float16)p0.z, (_Float16)p0.w,
                    (_Float16)p1.x, (_Float16)p1.y, (_Float16)p1.z, (_Float16)p1.w};
        af[rt][kt] = h;
      }
#pragma unroll
    for (int i = 0; i < 16; i++) {
      int idx = i * 256 + t;           // 0..4095
      int k = idx >> 5, n4 = (idx & 31) << 2;
      float4 wv = *reinterpret_cast<const float4*>(W1 + k * 128 + n4);
      WT[n4 + 0][k] = (_Float16)wv.x;
      WT[n4 + 1][k] = (_Float16)wv.y;
      WT[n4 + 2][k] = (_Float16)wv.z;
      WT[n4 + 3][k] = (_Float16)wv.w;
    }
    __syncthreads();
    floatx4 acc[2][8];
#pragma unroll
    for (int rt = 0; rt < 2; rt++)
#pragma unroll
      for (int ct = 0; ct < 8; ct++) acc[rt][ct] = {0.f, 0.f, 0.f, 0.f};
#pragma unroll
    for (int kt = 0; kt < 4; kt++) {
      half8v bf[8];
#pragma unroll
      for (int ct = 0; ct < 8; ct++)
        bf[ct] = *reinterpret_cast<const half8v*>(&WT[ct * 16 + l16][kt * 32 + quad * 8]);
#pragma unroll
      for (int rt = 0; rt < 2; rt++)
#pragma unroll
        for (int ct = 0; ct < 8; ct++)
          acc[rt][ct] = __builtin_amdgcn_mfma_f32_16x16x32_f16(af[rt][kt], bf[ct], acc[rt][ct], 0, 0, 0);
    }
#pragma unroll
    for (int rt = 0; rt < 2; rt++) {
#pragma unroll
      for (int r = 0; r < 4; r++) {
        long row = rowbase + rt * 16 + quad * 4 + r;
#pragma unroll
        for (int ct = 0; ct < 8; ct++)
          h16A[row * 128 + ct * 16 + l16] = (_Float16)acc[rt][ct][r];
      }
    }
  }
}

// ---------------- per-graph scan: offs, dis, per-chunk cursor bases ----------------
// Vectorized: single int4 pass over pIn held in registers; int4/float4 outputs.
__global__ __launch_bounds__(1024) void scan2_kernel(const int* __restrict__ pIn, int* __restrict__ offs,
                                                     int* __restrict__ cbase, float* __restrict__ dis) {
  __shared__ int part[1024];
  const int t = threadIdx.x;
  const int g = blockIdx.x;
  int4 cc[CPG];
#pragma unroll
  for (int c = 0; c < CPG; ++c)
    cc[c] = *reinterpret_cast<const int4*>(pIn + (((size_t)(g * CPG + c)) << 12) + t * 4);
  int4 tot = {0, 0, 0, 0};
#pragma unroll
  for (int c = 0; c < CPG; ++c) { tot.x += cc[c].x; tot.y += cc[c].y; tot.z += cc[c].z; tot.w += cc[c].w; }
  part[t] = tot.x + tot.y + tot.z + tot.w;
  __syncthreads();
  for (int off = 1; off < 1024; off <<= 1) {
    int add = (t >= off) ? part[t - off] : 0;
    __syncthreads();
    part[t] += add;
    __syncthreads();
  }
  const int run0 = (g << 16) + ((t == 0) ? 0 : part[t - 1]);
  int4 offv = {run0, run0 + tot.x, run0 + tot.x + tot.y, run0 + tot.x + tot.y + tot.z};
  *reinterpret_cast<int4*>(offs + (g << 12) + t * 4) = offv;
  float4 dv = {rsqrtf((float)tot.x + 1.0f), rsqrtf((float)tot.y + 1.0f),
               rsqrtf((float)tot.z + 1.0f), rsqrtf((float)tot.w + 1.0f)};
  *reinterpret_cast<float4*>(dis + (g << 12) + t * 4) = dv;
  int4 runv = offv;
#pragma unroll
  for (int c = 0; c < CPG; ++c) {
    *reinterpret_cast<int4*>(cbase + (((size_t)(g * CPG + c)) << 12) + t * 4) = runv;
    runv.x += cc[c].x; runv.y += cc[c].y; runv.z += cc[c].z; runv.w += cc[c].w;
  }
  if (g == 0 && t == 0) offs[NNODES] = NEDGES;
}

// ---------------- scatter via LDS cursors (int4 cbase staging) ----------------
__global__ __launch_bounds__(256) void scatter2_kernel(const int* __restrict__ src, const int* __restrict__ dst,
                                                       const int* __restrict__ cbase, int* __restrict__ ssrc) {
  __shared__ alignas(16) int cur[4096];
  const int t = threadIdx.x;
  const int g = blockIdx.x & 7;
  const int chunk = blockIdx.x >> 3;
  const int ebase = (g << 16) + (chunk << 12);
  const int nbase = g << 12;
  const int4* cb4 = reinterpret_cast<const int4*>(cbase + ((size_t)(g * CPG + chunk) << 12));
  int4* cur4 = reinterpret_cast<int4*>(cur);
#pragma unroll
  for (int i = 0; i < 4; i++) cur4[i * 256 + t] = cb4[i * 256 + t];
  __syncthreads();
  const int4* dst4 = reinterpret_cast<const int4*>(dst + ebase);
  const int4* src4 = reinterpret_cast<const int4*>(src + ebase);
#pragma unroll
  for (int i = 0; i < 4; ++i) {
    int4 d = dst4[i * 256 + t];
    int4 s = src4[i * 256 + t];
    int p0 = atomicAdd(&cur[d.x - nbase], 1); ssrc[p0] = s.x;
    int p1 = atomicAdd(&cur[d.y - nbase], 1); ssrc[p1] = s.y;
    int p2 = atomicAdd(&cur[d.z - nbase], 1); ssrc[p2] = s.z;
    int p3 = atomicAdd(&cur[d.w - nbase], 1); ssrc[p3] = s.w;
  }
}

// ---------------- MFMA fp16 GEMM: C[M x 128] = A[M x 128] @ W, W pre-transposed fp16 ----------------
template <int ACT, int BIAS, int SCALE, int AFP32>
__global__ __launch_bounds__(256) void mgemm_kernel(const void* __restrict__ Ain, const _Float16* __restrict__ WT16,
                                                    const float* __restrict__ bias, const float* __restrict__ rowscale,
                                                    _Float16* __restrict__ Cout) {
  __shared__ _Float16 WT[128][136];
  const int t = threadIdx.x;
  const int lane = t & 63;
  const int quad = lane >> 4, l16 = lane & 15;
  const long rowbase = (long)(blockIdx.x & 7) * 4096 + (long)(blockIdx.x >> 3) * 128 + (t >> 6) * 32;
  half8v af[2][4];
#pragma unroll
  for (int rt = 0; rt < 2; rt++)
#pragma unroll
    for (int kt = 0; kt < 4; kt++) {
      if (AFP32) {
        const float* A32 = (const float*)Ain;
        const float* p = A32 + (rowbase + rt * 16 + l16) * 128 + kt * 32 + quad * 8;
        float4 p0 = *reinterpret_cast<const float4*>(p);
        float4 p1 = *reinterpret_cast<const float4*>(p + 4);
        half8v h = {(_Float16)p0.x, (_Float16)p0.y, (_Float16)p0.z, (_Float16)p0.w,
                    (_Float16)p1.x, (_Float16)p1.y, (_Float16)p1.z, (_Float16)p1.w};
        af[rt][kt] = h;
      } else {
        const _Float16* A16 = (const _Float16*)Ain;
        af[rt][kt] = *reinterpret_cast<const half8v*>(A16 + (rowbase + rt * 16 + l16) * 128 + kt * 32 + quad * 8);
      }
    }
#pragma unroll
  for (int i = 0; i < 8; i++) {
    int idx = i * 256 + t;
    int n = idx >> 4, k8 = (idx & 15) << 3;
    *reinterpret_cast<half8v*>(&WT[n][k8]) = *reinterpret_cast<const half8v*>(&WT16[n * 128 + k8]);
  }
  __syncthreads();
  floatx4 acc[2][8];
#pragma unroll
  for (int rt = 0; rt < 2; rt++)
#pragma unroll
    for (int ct = 0; ct < 8; ct++) acc[rt][ct] = {0.f, 0.f, 0.f, 0.f};
#pragma unroll
  for (int kt = 0; kt < 4; kt++) {
    half8v bf[8];
#pragma unroll
    for (int ct = 0; ct < 8; ct++)
      bf[ct] = *reinterpret_cast<const half8v*>(&WT[ct * 16 + l16][kt * 32 + quad * 8]);
#pragma unroll
    for (int rt = 0; rt < 2; rt++)
#pragma unroll
      for (int ct = 0; ct < 8; ct++)
        acc[rt][ct] = __builtin_amdgcn_mfma_f32_16x16x32_f16(af[rt][kt], bf[ct], acc[rt][ct], 0, 0, 0);
  }
#pragma unroll
  for (int rt = 0; rt < 2; rt++) {
#pragma unroll
    for (int r = 0; r < 4; r++) {
      long row = rowbase + rt * 16 + quad * 4 + r;
      float sc = SCALE ? rowscale[row] : 1.f;
#pragma unroll
      for (int ct = 0; ct < 8; ct++) {
        float v = acc[rt][ct][r];
        if (SCALE) v *= sc;
        if (BIAS) v += bias[ct * 16 + l16];
        if (ACT == 1) v = fmaxf(v, 0.f);
        Cout[row * 128 + ct * 16 + l16] = (_Float16)v;
      }
    }
  }
}

// ---------------- fused assignment MLP: 512 blocks x 64 rows ----------------
__global__ __launch_bounds__(256) void mlp_kernel(const _Float16* __restrict__ h2, const _Float16* __restrict__ wta1,
                                                  const _Float16* __restrict__ wta2, const float* __restrict__ ba1,
                                                  const float* __restrict__ ba2, _Float16* __restrict__ sh) {
  __shared__ _Float16 WT1[128][136];
  __shared__ _Float16 Z[64][136];
  const int t = threadIdx.x;
  const int lane = t & 63;
  const int quad = lane >> 4, l16 = lane & 15;
  const int w = t >> 6;
  const long rowbase = (long)(blockIdx.x & 7) * 4096 + (long)(blockIdx.x >> 3) * 64 + w * 16;
  half8v af[4];
#pragma unroll
  for (int kt = 0; kt < 4; kt++)
    af[kt] = *reinterpret_cast<const half8v*>(h2 + (rowbase + l16) * 128 + kt * 32 + quad * 8);
#pragma unroll
  for (int i = 0; i < 8; i++) {
    int idx = i * 256 + t;
    int n = idx >> 4, k8 = (idx & 15) << 3;
    *reinterpret_cast<half8v*>(&WT1[n][k8]) = *reinterpret_cast<const half8v*>(&wta1[n * 128 + k8]);
  }
  __syncthreads();
  {
    floatx4 acc[8];
#pragma unroll
    for (int ct = 0; ct < 8; ct++) acc[ct] = {0.f, 0.f, 0.f, 0.f};
#pragma unroll
    for (int kt = 0; kt < 4; kt++) {
#pragma unroll
      for (int ct = 0; ct < 8; ct++) {
        half8v bf = *reinterpret_cast<const half8v*>(&WT1[ct * 16 + l16][kt * 32 + quad * 8]);
        acc[ct] = __builtin_amdgcn_mfma_f32_16x16x32_f16(af[kt], bf, acc[ct], 0, 0, 0);
      }
    }
#pragma unroll
    for (int r = 0; r < 4; r++) {
      int lrow = w * 16 + quad * 4 + r;
#pragma unroll
      for (int ct = 0; ct < 8; ct++) {
        float zx = acc[ct][r] + ba1[ct * 16 + l16];
        float ex = __expf(2.0f * zx);
        float v = 1.0f - 2.0f * __builtin_amdgcn_rcpf(ex + 1.0f);
        Z[lrow][ct * 16 + l16] = (_Float16)v;
      }
    }
  }
  __syncthreads();
#pragma unroll
  for (int i = 0; i < 4; i++) {
    int idx = i * 256 + t;
    int n = idx >> 4, k8 = (idx & 15) << 3;
    *reinterpret_cast<half8v*>(&WT1[n][k8]) = *reinterpret_cast<const half8v*>(&wta2[n * 128 + k8]);
  }
  half8v af2[4];
#pragma unroll
  for (int kt = 0; kt < 4; kt++)
    af2[kt] = *reinterpret_cast<const half8v*>(&Z[w * 16 + l16][kt * 32 + quad * 8]);
  __syncthreads();
  floatx4 acc2[4];
#pragma unroll
  for (int ct = 0; ct < 4; ct++) acc2[ct] = {0.f, 0.f, 0.f, 0.f};
#pragma unroll
  for (int kt = 0; kt < 4; kt++) {
#pragma unroll
    for (int ct = 0; ct < 4; ct++) {
      half8v bf = *reinterpret_cast<const half8v*>(&WT1[ct * 16 + l16][kt * 32 + quad * 8]);
      acc2[ct] = __builtin_amdgcn_mfma_f32_16x16x32_f16(af2[kt], bf, acc2[ct], 0, 0, 0);
    }
  }
#pragma unroll
  for (int r = 0; r < 4; r++) {
    long row = rowbase + quad * 4 + r;
    float v[4];
#pragma unroll
    for (int ct = 0; ct < 4; ct++) v[ct] = acc2[ct][r] + ba2[ct * 16 + l16];
    float m = fmaxf(fmaxf(v[0], v[1]), fmaxf(v[2], v[3]));
#pragma unroll
    for (int off = 1; off <= 8; off <<= 1) m = fmaxf(m, __shfl_xor(m, off, 64));
    float se = 0.f;
#pragma unroll
    for (int ct = 0; ct < 4; ct++) { v[ct] = __expf(v[ct] - m); se += v[ct]; }
#pragma unroll
    for (int off = 1; off <= 8; off <<= 1) se += __shfl_xor(se, off, 64);
    float inv = 1.0f / se;
#pragma unroll
    for (int ct = 0; ct < 4; ct++) v[ct] *= inv;
    float m2 = fmaxf(fmaxf(v[0], v[1]), fmaxf(v[2], v[3]));
#pragma unroll
    for (int off = 1; off <= 8; off <<= 1) m2 = fmaxf(m2, __shfl_xor(m2, off, 64));
    float se2 = 0.f;
#pragma unroll
    for (int ct = 0; ct < 4; ct++) { v[ct] = __expf(v[ct] - m2); se2 += v[ct]; }
#pragma unroll
    for (int off = 1; off <= 8; off <<= 1) se2 += __shfl_xor(se2, off, 64);
    float inv2 = 1.0f / se2;
#pragma unroll
    for (int ct = 0; ct < 4; ct++) sh[row * 64 + ct * 16 + l16] = (_Float16)(v[ct] * inv2);
  }
}

// ---------------- GCN aggregation: 16-stride main + one masked 16-tail ----------------
template <int RELU, int DISSRC>
__global__ __launch_bounds__(256) void aggregate_kernel(const _Float16* __restrict__ hs, const float* __restrict__ dis,
                                                        const int* __restrict__ offs, const int* __restrict__ ssrc,
                                                        const float* __restrict__ bias, _Float16* __restrict__ outh) {
  const int lane = threadIdx.x & 63;
  const int b = blockIdx.x;
  const int node = ((b & 7) << 12) + ((b >> 3) << 2) + (threadIdx.x >> 6);
  const int q = lane >> 4;
  const int fl = (lane & 15) * 8;
  const int e0 = offs[node], e1 = offs[node + 1];
  const float dn = dis[node];
  float fa[8];
#pragma unroll
  for (int j = 0; j < 8; j++) fa[j] = 0.f;
  int e = e0;
  for (; e + 16 <= e1; e += 16) {
    int s0 = ssrc[e + q];
    int s1 = ssrc[e + 4 + q];
    int s2 = ssrc[e + 8 + q];
    int s3 = ssrc[e + 12 + q];
    float d0 = 1.f, d1 = 1.f, d2 = 1.f, d3 = 1.f;
    if (DISSRC) { d0 = dis[s0]; d1 = dis[s1]; d2 = dis[s2]; d3 = dis[s3]; }
    half8v v0 = *reinterpret_cast<const half8v*>(hs + (size_t)s0 * 128 + fl);
    half8v v1 = *reinterpret_cast<const half8v*>(hs + (size_t)s1 * 128 + fl);
    half8v v2 = *reinterpret_cast<const half8v*>(hs + (size_t)s2 * 128 + fl);
    half8v v3 = *reinterpret_cast<const half8v*>(hs + (size_t)s3 * 128 + fl);
#pragma unroll
    for (int j = 0; j < 8; j++) {
      if (DISSRC) {
        fa[j] = fmaf(d0, (float)v0[j], fa[j]);
        fa[j] = fmaf(d1, (float)v1[j], fa[j]);
        fa[j] = fmaf(d2, (float)v2[j], fa[j]);
        fa[j] = fmaf(d3, (float)v3[j], fa[j]);
      } else {
        fa[j] += (float)v0[j] + (float)v1[j] + (float)v2[j] + (float)v3[j];
      }
    }
  }
  if (e < e1) {
    int last = e1 - 1;
    int s[4]; bool m[4];
#pragma unroll
    for (int jj = 0; jj < 4; jj++) {
      int idx = e + jj * 4 + q;
      m[jj] = idx < e1;
      int sv = ssrc[idx < last ? idx : last];
      s[jj] = m[jj] ? sv : node;
    }
#pragma unroll
    for (int jj = 0; jj < 4; jj++) {
      half8v v = *reinterpret_cast<const half8v*>(hs + (size_t)s[jj] * 128 + fl);
      float ds = DISSRC ? dis[s[jj]] : 1.f;
      if (m[jj]) {
#pragma unroll
        for (int j = 0; j < 8; j++) {
          if (DISSRC) fa[j] = fmaf(ds, (float)v[j], fa[j]);
          else fa[j] += (float)v[j];
        }
      }
    }
  }
#pragma unroll
  for (int j = 0; j < 8; j++) {
    fa[j] += __shfl_xor(fa[j], 16, 64);
    fa[j] += __shfl_xor(fa[j], 32, 64);
  }
  if (q == 0) {
    half8v self = *reinterpret_cast<const half8v*>(hs + (size_t)node * 128 + fl);
    float4 b0 = *reinterpret_cast<const float4*>(bias + fl);
    float4 b1 = *reinterpret_cast<const float4*>(bias + fl + 4);
    float bb[8] = {b0.x, b0.y, b0.z, b0.w, b1.x, b1.y, b1.z, b1.w};
    half8v r;
#pragma unroll
    for (int j = 0; j < 8; j++) {
      float acc = fa[j];
      if (DISSRC) acc = fmaf(dn, (float)self[j], acc);      // self row unscaled: dis_d * h_d
      else acc += (float)self[j];                            // self row pre-scaled by dis_d
      float v = fmaf(acc, dn, bb[j]);
      if (RELU) v = fmaxf(v, 0.f);
      r[j] = (_Float16)v;
    }
    *reinterpret_cast<half8v*>(outh + (size_t)node * 128 + fl) = r;
  }
}

// ---------------- G + den: 16-stride main + one masked 16-tail ----------------
__global__ __launch_bounds__(256) void gather_kernel(const _Float16* __restrict__ sh, const int* __restrict__ offs,
                                                     const int* __restrict__ ssrc, _Float16* __restrict__ Gh,
                                                     float* __restrict__ dnp) {
  const int lane = threadIdx.x & 63;
  const int b = blockIdx.x;
  const int node = ((b & 7) << 12) + ((b >> 3) << 2) + (threadIdx.x >> 6);
  const int q = lane >> 3;
  const int fl = (lane & 7) * 8;
  const int e0 = offs[node], e1 = offs[node + 1];
  float fa[8];
  float sq = 0.f;
#pragma unroll
  for (int j = 0; j < 8; j++) fa[j] = 0.f;
  int e = e0;
  for (; e + 16 <= e1; e += 16) {
    int s0 = ssrc[e + q];
    int s1 = ssrc[e + 8 + q];
    half8v v0 = *reinterpret_cast<const half8v*>(sh + (size_t)s0 * 64 + fl);
    half8v v1 = *reinterpret_cast<const half8v*>(sh + (size_t)s1 * 64 + fl);
#pragma unroll
    for (int j = 0; j < 8; j++) {
      float f0 = (float)v0[j], f1 = (float)v1[j];
      fa[j] += f0 + f1;
      sq = fmaf(f0, f0, sq);
      sq = fmaf(f1, f1, sq);
    }
  }
  if (e < e1) {
    int last = e1 - 1;
    int i0 = e + q, i1 = e + 8 + q;
    bool m0 = i0 < e1, m1 = i1 < e1;
    int sv0 = ssrc[i0 < last ? i0 : last];
    int sv1 = ssrc[i1 < last ? i1 : last];
    int s0 = m0 ? sv0 : node;
    int s1 = m1 ? sv1 : node;
    half8v v0 = *reinterpret_cast<const half8v*>(sh + (size_t)s0 * 64 + fl);
    half8v v1 = *reinterpret_cast<const half8v*>(sh + (size_t)s1 * 64 + fl);
#pragma unroll
    for (int j = 0; j < 8; j++) {
      float f0 = m0 ? (float)v0[j] : 0.f;
      float f1 = m1 ? (float)v1[j] : 0.f;
      fa[j] += f0 + f1;
      sq = fmaf(f0, f0, sq);
      sq = fmaf(f1, f1, sq);
    }
  }
#pragma unroll
  for (int j = 0; j < 8; j++) {
    fa[j] += __shfl_xor(fa[j], 8, 64);
    fa[j] += __shfl_xor(fa[j], 16, 64);
    fa[j] += __shfl_xor(fa[j], 32, 64);
  }
  float den = wave_sum(sq);
  if (lane == 0) dnp[node] = den;
  if (q == 0) {
    half8v r;
#pragma unroll
    for (int j = 0; j < 8; j++) r[j] = (_Float16)fa[j];
    *reinterpret_cast<half8v*>(Gh + (size_t)node * 64 + fl) = r;
  }
}

// ---------------- rank reduction via MFMA: C[64 x 256] = s_chunk^T [G | s | h2] ----------------
__global__ __launch_bounds__(512) void atb_kernel(const _Float16* __restrict__ sh, const _Float16* __restrict__ Gh,
                                                  const _Float16* __restrict__ h2, float* __restrict__ pF) {
  __shared__ _Float16 XsT[64][136];   // [cluster m][node k 0..127]
  __shared__ _Float16 YsT[256][40];   // [col n][node k 0..31 within kt]
  const int t = threadIdx.x;
  const int g = blockIdx.x & 7, chunk = blockIdx.x >> 3;
  const int n0 = g * 4096 + chunk * 128;
  const int lane = t & 63;
  const int w = t >> 6;
  const int mtile = w & 3;
  const int nhalf = w >> 2;
  const int quad = lane >> 4, l16 = lane & 15;

#pragma unroll
  for (int i = 0; i < 4; i++) {
    int slot = i * 512 + t;
    int k = slot >> 4, c4 = (slot & 15) * 4;
    half4v v = *reinterpret_cast<const half4v*>(&sh[(size_t)(n0 + k) * 64 + c4]);
#pragma unroll
    for (int j = 0; j < 4; j++) XsT[c4 + j][k] = v[j];
  }

  floatx4 acc[8];
#pragma unroll
  for (int nt = 0; nt < 8; nt++) acc[nt] = {0.f, 0.f, 0.f, 0.f};

  for (int kt = 0; kt < 4; ++kt) {
    const int nb = n0 + kt * 32;
    __syncthreads();
#pragma unroll
    for (int i = 0; i < 4; i++) {
      int slot = i * 512 + t;
      int cg = slot & 15, k = (slot >> 4) & 31, ch = slot >> 9;
      int c = ch * 64 + cg * 4;
      half4v v;
      if (c < 64)       v = *reinterpret_cast<const half4v*>(&Gh[(size_t)(nb + k) * 64 + c]);
      else if (c < 128) v = *reinterpret_cast<const half4v*>(&sh[(size_t)(nb + k) * 64 + (c - 64)]);
      else              v = *reinterpret_cast<const half4v*>(&h2[(size_t)(nb + k) * 128 + (c - 128)]);
#pragma unroll
      for (int j = 0; j < 4; j++) YsT[c + j][k] = v[j];
    }
    __syncthreads();
    half8v af = *reinterpret_cast<const half8v*>(&XsT[mtile * 16 + l16][kt * 32 + quad * 8]);
#pragma unroll
    for (int nt = 0; nt < 8; nt++) {
      half8v bf = *reinterpret_cast<const half8v*>(&YsT[(nhalf * 8 + nt) * 16 + l16][quad * 8]);
      acc[nt] = __builtin_amdgcn_mfma_f32_16x16x32_f16(af, bf, acc[nt], 0, 0, 0);
    }
  }
  float* dst = pF + (size_t)blockIdx.x * 16384;
#pragma unroll
  for (int nt = 0; nt < 8; nt++) {
#pragma unroll
    for (int r = 0; r < 4; r++) {
      dst[(mtile * 16 + quad * 4 + r) * 256 + (nhalf * 8 + nt) * 16 + l16] = acc[nt][r];
    }
  }
}

// ---------------- merge 32 partials/graph -> oadj, ssb, outp16 ----------------
__global__ __launch_bounds__(256) void merge_kernel(const float* __restrict__ pF, float* __restrict__ oadj,
                                                    float* __restrict__ ssb, _Float16* __restrict__ outp16) {
  int g = blockIdx.x & 7;
  int o4 = (blockIdx.x >> 3) * 256 + threadIdx.x;
  float sx = 0.f, sy = 0.f, sz = 0.f, sw = 0.f;
#pragma unroll
  for (int q = 0; q < 32; ++q) {
    float4 v = *reinterpret_cast<const float4*>(pF + (size_t)(q * 8 + g) * 16384 + o4 * 4);
    sx += v.x; sy += v.y; sz += v.z; sw += v.w;
  }
  int row = o4 >> 6;
  int c = (o4 & 63) * 4;
  if (c < 64) {
    float4 o = {sx, sy, sz, sw};
    *reinterpret_cast<float4*>(&oadj[g * 4096 + row * 64 + c]) = o;
  } else if (c < 128) {
    float4 o = {sx, sy, sz, sw};
    *reinterpret_cast<float4*>(&ssb[g * 4096 + row * 64 + (c - 64)]) = o;
  } else {
    half4v h = {(_Float16)sx, (_Float16)sy, (_Float16)sz, (_Float16)sw};
    *reinterpret_cast<half4v*>(&outp16[g * 8192 + row * 128 + (c - 128)]) = h;
  }
}

// ---------------- epilogue2: losses + adj-norm + pooled MFMA GEMM (8 blocks) ----------------
__global__ __launch_bounds__(256) void epilogue2_kernel(const float* __restrict__ oadj, const float* __restrict__ ssb,
                                                        const _Float16* __restrict__ outp16, const _Float16* __restrict__ wto,
                                                        const float* __restrict__ bo, const float* __restrict__ dn,
                                                        float* __restrict__ out) {
  __shared__ _Float16 outpS[64][136];
  __shared__ _Float16 WoT[128][136];
  __shared__ float red[256];
  __shared__ float rowsum[64];
  __shared__ float dw[4], w1[4], w2[4], w3[4];
  const int g = blockIdx.x, t = threadIdx.x;

#pragma unroll
  for (int i = 0; i < 8; i++) {
    int idx = i * 256 + t;
    int n = idx >> 4, k8 = (idx & 15) << 3;
    *reinterpret_cast<half8v*>(&WoT[n][k8]) = *reinterpret_cast<const half8v*>(&wto[n * 128 + k8]);
  }
#pragma unroll
  for (int i = 0; i < 4; i++) {
    int idx = i * 256 + t;
    int orow = idx >> 4, c8 = (idx & 15) * 8;
    half8v v = *reinterpret_cast<const half8v*>(&outp16[g * 8192 + orow * 128 + c8]);
    *reinterpret_cast<half8v*>(&outpS[orow][c8]) = v;
  }

  const int row = t >> 2, p = t & 3;
  float Areg[16];
  float trs_p = 0.f, ssq_p = 0.f;
#pragma unroll
  for (int c4 = 0; c4 < 4; c4++) {
    float4 a = *reinterpret_cast<const float4*>(&oadj[g * 4096 + row * 64 + p * 16 + c4 * 4]);
    Areg[c4 * 4 + 0] = a.x; Areg[c4 * 4 + 1] = a.y; Areg[c4 * 4 + 2] = a.z; Areg[c4 * 4 + 3] = a.w;
    float4 s = *reinterpret_cast<const float4*>(&ssb[g * 4096 + row * 64 + p * 16 + c4 * 4]);
    float vv[4] = {s.x, s.y, s.z, s.w};
#pragma unroll
    for (int jj = 0; jj < 4; jj++) {
      ssq_p += vv[jj] * vv[jj];
      int col = p * 16 + c4 * 4 + jj;
      if (col == row) trs_p += vv[jj];
    }
  }
  float da = 0.f;
#pragma unroll
  for (int i = 0; i < 16; i++) da += dn[g * 4096 + i * 256 + t];
  float dws = wave_sum(da);
  if ((t & 63) == 0) dw[t >> 6] = dws;

  float rs = 0.f, tra = 0.f;
#pragma unroll
  for (int c = 0; c < 16; c++) {
    int j = p * 16 + c;
    if (j == row) tra += Areg[c];
    else rs += Areg[c];
  }
  red[t] = rs;
  __syncthreads();
  if (p == 0) rowsum[row] = red[t] + red[t + 1] + red[t + 2] + red[t + 3];
  float v1 = wave_sum(tra), v2 = wave_sum(trs_p), v3 = wave_sum(ssq_p);
  if ((t & 63) == 0) { int w = t >> 6; w1[w] = v1; w2[w] = v2; w3[w] = v3; }
  __syncthreads();
  if (t == 0) {
    float TRA = w1[0] + w1[1] + w1[2] + w1[3];
    float TRS = w2[0] + w2[1] + w2[2] + w2[3];
    float SSQ = w3[0] + w3[1] + w3[2] + w3[3];
    float DEN = dw[0] + dw[1] + dw[2] + dw[3];
    atomicAdd(&out[98816], -(TRA / DEN) * 0.125f);
    float ssn = sqrtf(SSQ);
    atomicAdd(&out[98817], sqrtf(2.0f - TRS / (4.0f * ssn)) * 0.125f);
  }
  float di = sqrtf(rowsum[row]) + 1e-15f;
#pragma unroll
  for (int c = 0; c < 16; c++) {
    int j = p * 16 + c;
    float v = (j == row) ? 0.f : Areg[c];
    float dj = sqrtf(rowsum[j]) + 1e-15f;
    out[65536 + g * 4096 + row * 64 + j] = v / (di * dj);
  }
  if (t < 64) out[98304 + g * 64 + t] = (float)g;

  const int lane = t & 63;
  const int quad = lane >> 4, l16 = lane & 15;
  const int w = t >> 6;
  floatx4 acc[8];
#pragma unroll
  for (int ct = 0; ct < 8; ct++) acc[ct] = {0.f, 0.f, 0.f, 0.f};
#pragma unroll
  for (int kt = 0; kt < 4; kt++) {
    half8v af = *reinterpret_cast<const half8v*>(&outpS[w * 16 + l16][kt * 32 + quad * 8]);
#pragma unroll
    for (int ct = 0; ct < 8; ct++) {
      half8v bf = *reinterpret_cast<const half8v*>(&WoT[ct * 16 + l16][kt * 32 + quad * 8]);
      acc[ct] = __builtin_amdgcn_mfma_f32_16x16x32_f16(af, bf, acc[ct], 0, 0, 0);
    }
  }
#pragma unroll
  for (int r = 0; r < 4; r++) {
    int orow = w * 16 + quad * 4 + r;
#pragma unroll
    for (int ct = 0; ct < 8; ct++) {
      int col = ct * 16 + l16;
      float v = fmaxf(acc[ct][r] + bo[col], 0.f);
      out[(g * 64 + orow) * 128 + col] = v;
    }
  }
}

extern "C" void kernel_launch(void* const* d_in, const int* in_sizes, int n_in,
                              void* d_out, int out_size, void* d_ws, size_t ws_size,
                              hipStream_t stream) {
  const float* x   = (const float*)d_in[0];
  const int*   ei  = (const int*)d_in[1];
  const float* W1  = (const float*)d_in[3];
  const float* b1  = (const float*)d_in[4];
  const float* W2  = (const float*)d_in[5];
  const float* b2  = (const float*)d_in[6];
  const float* Wa1 = (const float*)d_in[7];
  const float* ba1 = (const float*)d_in[8];
  const float* Wa2 = (const float*)d_in[9];
  const float* ba2 = (const float*)d_in[10];
  const float* Wo  = (const float*)d_in[11];
  const float* bo  = (const float*)d_in[12];
  const int* src = ei;
  const int* dst = ei + NEDGES;
  float* out = (float*)d_out;

  char* ws = (char*)d_ws;
  size_t o = 0;
  auto alloc = [&](size_t bytes) -> void* {
    void* p = ws + o;
    o += (bytes + 255) & ~(size_t)255;
    return p;
  };
  _Float16* h16A = (_Float16*)alloc((size_t)NNODES * 128 * 2);
  _Float16* h16B = (_Float16*)alloc((size_t)NNODES * 128 * 2);
  _Float16* h16C = (_Float16*)alloc((size_t)NNODES * 128 * 2);
  _Float16* sh   = (_Float16*)alloc((size_t)NNODES * 64 * 2);
  _Float16* Gh   = (_Float16*)alloc((size_t)NNODES * 64 * 2);
  float* pF    = (float*)alloc((size_t)256 * 16384 * 4);
  float* dis   = (float*)alloc((size_t)NNODES * 4);
  int* offs    = (int*)alloc((size_t)(NNODES + 1) * 4);
  int* ssrc    = (int*)alloc((size_t)NEDGES * 4);
  int* pIn     = (int*)alloc((size_t)8 * CPG * 4096 * 4);
  int* cbase   = (int*)alloc((size_t)8 * CPG * 4096 * 4);
  float* dn    = (float*)alloc((size_t)NNODES * 4);
  float* oadj  = (float*)alloc(8 * 4096 * 4);
  float* ssb   = (float*)alloc(8 * 4096 * 4);
  _Float16* outp16 = (_Float16*)alloc(8 * 8192 * 2);
  _Float16* wt16   = (_Float16*)alloc((size_t)WT_TOTAL * 2);

  // 1: histogram (blocks 0..127) || layer-1 GEMM (blocks 128..383, unscaled)
  histgemm1_kernel<<<384, 256, 0, stream>>>(src, dst, pIn, W1, W2, Wa1, Wa2, Wo, wt16, x, h16A, out);
  // 2-3: CSR build (LDS-cursor scatter; int4 staging everywhere)
  scan2_kernel<<<8, 1024, 0, stream>>>(pIn, offs, cbase, dis);
  scatter2_kernel<<<8 * CPG, 256, 0, stream>>>(src, dst, cbase, ssrc);

  // layer 1 aggregate: per-edge dis[src] (deferred producer scale) + dis[dst], bias, relu
  aggregate_kernel<1, 1><<<NNODES / 4, 256, 0, stream>>>(h16A, dis, offs, ssrc, b1, h16B);
  mgemm_kernel<0, 0, 1, 0><<<NNODES / 128, 256, 0, stream>>>(h16B, wt16 + WT2_OFF, nullptr, dis, h16A);
  aggregate_kernel<0, 0><<<NNODES / 4, 256, 0, stream>>>(h16A, dis, offs, ssrc, b2, h16C);

  mlp_kernel<<<NNODES / 64, 256, 0, stream>>>(h16C, wt16 + WTA1_OFF, wt16 + WTA2_OFF, ba1, ba2, sh);

  gather_kernel<<<NNODES / 4, 256, 0, stream>>>(sh, offs, ssrc, Gh, dn);
  atb_kernel<<<256, 512, 0, stream>>>(sh, Gh, h16C, pF);
  merge_kernel<<<128, 256, 0, stream>>>(pF, oadj, ssb, outp16);
  epilogue2_kernel<<<8, 256, 0, stream>>>(oadj, ssb, outp16, wt16 + WTO_OFF, bo, dn, out);
}

// Round 7
// 186.610 us; speedup vs baseline: 1.0900x; 1.0042x over previous
//
#include <hip/hip_runtime.h>

#define NNODES 32768
#define NEDGES 524288
#define KCL 64
#define CPG 16   // histogram chunks per graph (4096 edges each)

typedef _Float16 half8v __attribute__((ext_vector_type(8)));
typedef _Float16 half4v __attribute__((ext_vector_type(4)));
typedef float floatx4 __attribute__((ext_vector_type(4)));

// fp16 transposed weight buffer layout (element offsets into wt16):
#define WT1_OFF   0       // W1  [128x128] -> [n*128+k]  (unused; layout stability)
#define WT2_OFF   16384   // W2  [128x128]
#define WTA1_OFF  32768   // Wa1 [128x128]
#define WTA2_OFF  49152   // Wa2 [128x64]  -> [n*128+k], n<64
#define WTO_OFF   57344   // Wo  [128x128]
#define WT_TOTAL  73728

__device__ __forceinline__ float wave_sum(float v) {
#pragma unroll
  for (int off = 32; off > 0; off >>= 1) v += __shfl_xor(v, off, 64);
  return v;
}

// ---------------- fused: per-chunk LDS histogram + weight prep (blocks 0..127)
// ----------------        ∥ layer-1 GEMM h16A = fp16(x @ W1), UNSCALED (blocks 128..383)
__global__ __launch_bounds__(256) void histgemm1_kernel(const int* __restrict__ src, const int* __restrict__ dst,
                                                        int* __restrict__ pIn,
                                                        const float* __restrict__ W1, const float* __restrict__ W2,
                                                        const float* __restrict__ Wa1, const float* __restrict__ Wa2,
                                                        const float* __restrict__ Wo, _Float16* __restrict__ wt16,
                                                        const float* __restrict__ x, _Float16* __restrict__ h16A,
                                                        float* __restrict__ out) {
  __shared__ alignas(16) _Float16 WT[128][136];
  const int t = threadIdx.x;
  if (blockIdx.x < 128) {
    int* hIn = reinterpret_cast<int*>(&WT[0][0]);
    const int g = blockIdx.x & 7;
    const int chunk = blockIdx.x >> 3;
    const int ebase = (g << 16) + (chunk << 12);
    const int nbase = g << 12;
    if (blockIdx.x == 0 && t < 2) out[98816 + t] = 0.f;  // zero loss accumulators
    {
      int4 z = {0, 0, 0, 0};
      int4* h4 = reinterpret_cast<int4*>(hIn);
#pragma unroll
      for (int i = 0; i < 4; i++) h4[i * 256 + t] = z;
    }
    __syncthreads();
    {
      int tg = blockIdx.x * 256 + t;
#pragma unroll
      for (int i = 0; i < 3; i++) {
        int id = tg + i * 32768;
        if (id < WT_TOTAL) {
          const float* W; int base, lb;
          if (id < 16384)      { W = W1;  base = WT1_OFF;  lb = 7; }
          else if (id < 32768) { W = W2;  base = WT2_OFF;  lb = 7; }
          else if (id < 49152) { W = Wa1; base = WTA1_OFF; lb = 7; }
          else if (id < 57344) { W = Wa2; base = WTA2_OFF; lb = 6; }
          else                 { W = Wo;  base = WTO_OFF;  lb = 7; }
          int m = id - base;
          int k = m >> lb, n = m & ((1 << lb) - 1);
          wt16[base + n * 128 + k] = (_Float16)W[m];
        }
      }
    }
    const int4* dst4 = reinterpret_cast<const int4*>(dst + ebase);
#pragma unroll
    for (int i = 0; i < 4; ++i) {
      int4 d = dst4[i * 256 + t];
      atomicAdd(&hIn[d.x - nbase], 1);
      atomicAdd(&hIn[d.y - nbase], 1);
      atomicAdd(&hIn[d.z - nbase], 1);
      atomicAdd(&hIn[d.w - nbase], 1);
    }
    __syncthreads();
    int4* dIn4 = reinterpret_cast<int4*>(pIn + ((size_t)(g * CPG + chunk) << 12));
    const int4* h4 = reinterpret_cast<const int4*>(hIn);
#pragma unroll
    for (int i = 0; i < 4; i++) dIn4[i * 256 + t] = h4[i * 256 + t];
  } else {
    const int bid = blockIdx.x - 128;
    const int lane = t & 63;
    const int quad = lane >> 4, l16 = lane & 15;
    const long rowbase = (long)(bid & 7) * 4096 + (long)(bid >> 3) * 128 + (t >> 6) * 32;
    half8v af[2][4];
#pragma unroll
    for (int rt = 0; rt < 2; rt++)
#pragma unroll
      for (int kt = 0; kt < 4; kt++) {
        const float* p = x + (rowbase + rt * 16 + l16) * 128 + kt * 32 + quad * 8;
        float4 p0 = *reinterpret_cast<const float4*>(p);
        float4 p1 = *reinterpret_cast<const float4*>(p + 4);
        half8v h = {(_Float16)p0.x, (_Float16)p0.y, (_Float16)p0.z, (_Float16)p0.w,
                    (_Float16)p1.x, (_Float16)p1.y, (_Float16)p1.z, (_Float16)p1.w};
        af[rt][kt] = h;
      }
#pragma unroll
    for (int i = 0; i < 16; i++) {
      int idx = i * 256 + t;           // 0..4095
      int k = idx >> 5, n4 = (idx & 31) << 2;
      float4 wv = *reinterpret_cast<const float4*>(W1 + k * 128 + n4);
      WT[n4 + 0][k] = (_Float16)wv.x;
      WT[n4 + 1][k] = (_Float16)wv.y;
      WT[n4 + 2][k] = (_Float16)wv.z;
      WT[n4 + 3][k] = (_Float16)wv.w;
    }
    __syncthreads();
    floatx4 acc[2][8];
#pragma unroll
    for (int rt = 0; rt < 2; rt++)
#pragma unroll
      for (int ct = 0; ct < 8; ct++) acc[rt][ct] = {0.f, 0.f, 0.f, 0.f};
#pragma unroll
    for (int kt = 0; kt < 4; kt++) {
      half8v bf[8];
#pragma unroll
      for (int ct = 0; ct < 8; ct++)
        bf[ct] = *reinterpret_cast<const half8v*>(&WT[ct * 16 + l16][kt * 32 + quad * 8]);
#pragma unroll
      for (int rt = 0; rt < 2; rt++)
#pragma unroll
        for (int ct = 0; ct < 8; ct++)
          acc[rt][ct] = __builtin_amdgcn_mfma_f32_16x16x32_f16(af[rt][kt], bf[ct], acc[rt][ct], 0, 0, 0);
    }
#pragma unroll
    for (int rt = 0; rt < 2; rt++) {
#pragma unroll
      for (int r = 0; r < 4; r++) {
        long row = rowbase + rt * 16 + quad * 4 + r;
#pragma unroll
        for (int ct = 0; ct < 8; ct++)
          h16A[row * 128 + ct * 16 + l16] = (_Float16)acc[rt][ct][r];
      }
    }
  }
}

// ---------------- per-graph scan: offs, dis, per-chunk cursor bases ----------------
// int4 single pass; two-level shuffle scan (1 barrier instead of 20).
__global__ __launch_bounds__(1024) void scan2_kernel(const int* __restrict__ pIn, int* __restrict__ offs,
                                                     int* __restrict__ cbase, float* __restrict__ dis) {
  __shared__ int wsum[16];
  const int t = threadIdx.x;
  const int g = blockIdx.x;
  const int lane = t & 63, wid = t >> 6;
  int4 cc[CPG];
#pragma unroll
  for (int c = 0; c < CPG; ++c)
    cc[c] = *reinterpret_cast<const int4*>(pIn + (((size_t)(g * CPG + c)) << 12) + t * 4);
  int4 tot = {0, 0, 0, 0};
#pragma unroll
  for (int c = 0; c < CPG; ++c) { tot.x += cc[c].x; tot.y += cc[c].y; tot.z += cc[c].z; tot.w += cc[c].w; }
  const int s = tot.x + tot.y + tot.z + tot.w;
  // intra-wave inclusive scan of s
  int ps = s;
#pragma unroll
  for (int off = 1; off < 64; off <<= 1) {
    int v = __shfl_up(ps, off, 64);
    if (lane >= off) ps += v;
  }
  if (lane == 63) wsum[wid] = ps;
  __syncthreads();
  // scan the 16 wave totals within each wave (broadcast LDS read + 4-step shfl scan)
  int wv = (lane < 16) ? wsum[lane] : 0;
#pragma unroll
  for (int off = 1; off < 16; off <<= 1) {
    int u = __shfl_up(wv, off, 64);
    if (lane >= off) wv += u;
  }
  const int wbase = (wid == 0) ? 0 : __shfl(wv, wid - 1, 64);
  const int run0 = (g << 16) + wbase + (ps - s);   // exclusive prefix, identical to old scan
  int4 offv = {run0, run0 + tot.x, run0 + tot.x + tot.y, run0 + tot.x + tot.y + tot.z};
  *reinterpret_cast<int4*>(offs + (g << 12) + t * 4) = offv;
  float4 dv = {rsqrtf((float)tot.x + 1.0f), rsqrtf((float)tot.y + 1.0f),
               rsqrtf((float)tot.z + 1.0f), rsqrtf((float)tot.w + 1.0f)};
  *reinterpret_cast<float4*>(dis + (g << 12) + t * 4) = dv;
  int4 runv = offv;
#pragma unroll
  for (int c = 0; c < CPG; ++c) {
    *reinterpret_cast<int4*>(cbase + (((size_t)(g * CPG + c)) << 12) + t * 4) = runv;
    runv.x += cc[c].x; runv.y += cc[c].y; runv.z += cc[c].z; runv.w += cc[c].w;
  }
  if (g == 0 && t == 0) offs[NNODES] = NEDGES;
}

// ---------------- scatter via LDS cursors (int4 cbase staging) ----------------
__global__ __launch_bounds__(256) void scatter2_kernel(const int* __restrict__ src, const int* __restrict__ dst,
                                                       const int* __restrict__ cbase, int* __restrict__ ssrc) {
  __shared__ alignas(16) int cur[4096];
  const int t = threadIdx.x;
  const int g = blockIdx.x & 7;
  const int chunk = blockIdx.x >> 3;
  const int ebase = (g << 16) + (chunk << 12);
  const int nbase = g << 12;
  const int4* cb4 = reinterpret_cast<const int4*>(cbase + ((size_t)(g * CPG + chunk) << 12));
  int4* cur4 = reinterpret_cast<int4*>(cur);
#pragma unroll
  for (int i = 0; i < 4; i++) cur4[i * 256 + t] = cb4[i * 256 + t];
  __syncthreads();
  const int4* dst4 = reinterpret_cast<const int4*>(dst + ebase);
  const int4* src4 = reinterpret_cast<const int4*>(src + ebase);
#pragma unroll
  for (int i = 0; i < 4; ++i) {
    int4 d = dst4[i * 256 + t];
    int4 s = src4[i * 256 + t];
    int p0 = atomicAdd(&cur[d.x - nbase], 1); ssrc[p0] = s.x;
    int p1 = atomicAdd(&cur[d.y - nbase], 1); ssrc[p1] = s.y;
    int p2 = atomicAdd(&cur[d.z - nbase], 1); ssrc[p2] = s.z;
    int p3 = atomicAdd(&cur[d.w - nbase], 1); ssrc[p3] = s.w;
  }
}

// ---------------- MFMA fp16 GEMM: C[M x 128] = A[M x 128] @ W, W pre-transposed fp16 ----------------
template <int ACT, int BIAS, int SCALE, int AFP32>
__global__ __launch_bounds__(256) void mgemm_kernel(const void* __restrict__ Ain, const _Float16* __restrict__ WT16,
                                                    const float* __restrict__ bias, const float* __restrict__ rowscale,
                                                    _Float16* __restrict__ Cout) {
  __shared__ _Float16 WT[128][136];
  const int t = threadIdx.x;
  const int lane = t & 63;
  const int quad = lane >> 4, l16 = lane & 15;
  const long rowbase = (long)(blockIdx.x & 7) * 4096 + (long)(blockIdx.x >> 3) * 128 + (t >> 6) * 32;
  half8v af[2][4];
#pragma unroll
  for (int rt = 0; rt < 2; rt++)
#pragma unroll
    for (int kt = 0; kt < 4; kt++) {
      if (AFP32) {
        const float* A32 = (const float*)Ain;
        const float* p = A32 + (rowbase + rt * 16 + l16) * 128 + kt * 32 + quad * 8;
        float4 p0 = *reinterpret_cast<const float4*>(p);
        float4 p1 = *reinterpret_cast<const float4*>(p + 4);
        half8v h = {(_Float16)p0.x, (_Float16)p0.y, (_Float16)p0.z, (_Float16)p0.w,
                    (_Float16)p1.x, (_Float16)p1.y, (_Float16)p1.z, (_Float16)p1.w};
        af[rt][kt] = h;
      } else {
        const _Float16* A16 = (const _Float16*)Ain;
        af[rt][kt] = *reinterpret_cast<const half8v*>(A16 + (rowbase + rt * 16 + l16) * 128 + kt * 32 + quad * 8);
      }
    }
#pragma unroll
  for (int i = 0; i < 8; i++) {
    int idx = i * 256 + t;
    int n = idx >> 4, k8 = (idx & 15) << 3;
    *reinterpret_cast<half8v*>(&WT[n][k8]) = *reinterpret_cast<const half8v*>(&WT16[n * 128 + k8]);
  }
  __syncthreads();
  floatx4 acc[2][8];
#pragma unroll
  for (int rt = 0; rt < 2; rt++)
#pragma unroll
    for (int ct = 0; ct < 8; ct++) acc[rt][ct] = {0.f, 0.f, 0.f, 0.f};
#pragma unroll
  for (int kt = 0; kt < 4; kt++) {
    half8v bf[8];
#pragma unroll
    for (int ct = 0; ct < 8; ct++)
      bf[ct] = *reinterpret_cast<const half8v*>(&WT[ct * 16 + l16][kt * 32 + quad * 8]);
#pragma unroll
    for (int rt = 0; rt < 2; rt++)
#pragma unroll
      for (int ct = 0; ct < 8; ct++)
        acc[rt][ct] = __builtin_amdgcn_mfma_f32_16x16x32_f16(af[rt][kt], bf[ct], acc[rt][ct], 0, 0, 0);
  }
#pragma unroll
  for (int rt = 0; rt < 2; rt++) {
#pragma unroll
    for (int r = 0; r < 4; r++) {
      long row = rowbase + rt * 16 + quad * 4 + r;
      float sc = SCALE ? rowscale[row] : 1.f;
#pragma unroll
      for (int ct = 0; ct < 8; ct++) {
        float v = acc[rt][ct][r];
        if (SCALE) v *= sc;
        if (BIAS) v += bias[ct * 16 + l16];
        if (ACT == 1) v = fmaxf(v, 0.f);
        Cout[row * 128 + ct * 16 + l16] = (_Float16)v;
      }
    }
  }
}

// ---------------- fused assignment MLP: 512 blocks x 64 rows ----------------
__global__ __launch_bounds__(256) void mlp_kernel(const _Float16* __restrict__ h2, const _Float16* __restrict__ wta1,
                                                  const _Float16* __restrict__ wta2, const float* __restrict__ ba1,
                                                  const float* __restrict__ ba2, _Float16* __restrict__ sh) {
  __shared__ _Float16 WT1[128][136];
  __shared__ _Float16 Z[64][136];
  const int t = threadIdx.x;
  const int lane = t & 63;
  const int quad = lane >> 4, l16 = lane & 15;
  const int w = t >> 6;
  const long rowbase = (long)(blockIdx.x & 7) * 4096 + (long)(blockIdx.x >> 3) * 64 + w * 16;
  half8v af[4];
#pragma unroll
  for (int kt = 0; kt < 4; kt++)
    af[kt] = *reinterpret_cast<const half8v*>(h2 + (rowbase + l16) * 128 + kt * 32 + quad * 8);
#pragma unroll
  for (int i = 0; i < 8; i++) {
    int idx = i * 256 + t;
    int n = idx >> 4, k8 = (idx & 15) << 3;
    *reinterpret_cast<half8v*>(&WT1[n][k8]) = *reinterpret_cast<const half8v*>(&wta1[n * 128 + k8]);
  }
  __syncthreads();
  {
    floatx4 acc[8];
#pragma unroll
    for (int ct = 0; ct < 8; ct++) acc[ct] = {0.f, 0.f, 0.f, 0.f};
#pragma unroll
    for (int kt = 0; kt < 4; kt++) {
#pragma unroll
      for (int ct = 0; ct < 8; ct++) {
        half8v bf = *reinterpret_cast<const half8v*>(&WT1[ct * 16 + l16][kt * 32 + quad * 8]);
        acc[ct] = __builtin_amdgcn_mfma_f32_16x16x32_f16(af[kt], bf, acc[ct], 0, 0, 0);
      }
    }
#pragma unroll
    for (int r = 0; r < 4; r++) {
      int lrow = w * 16 + quad * 4 + r;
#pragma unroll
      for (int ct = 0; ct < 8; ct++) {
        float zx = acc[ct][r] + ba1[ct * 16 + l16];
        float ex = __expf(2.0f * zx);
        float v = 1.0f - 2.0f * __builtin_amdgcn_rcpf(ex + 1.0f);
        Z[lrow][ct * 16 + l16] = (_Float16)v;
      }
    }
  }
  __syncthreads();
#pragma unroll
  for (int i = 0; i < 4; i++) {
    int idx = i * 256 + t;
    int n = idx >> 4, k8 = (idx & 15) << 3;
    *reinterpret_cast<half8v*>(&WT1[n][k8]) = *reinterpret_cast<const half8v*>(&wta2[n * 128 + k8]);
  }
  half8v af2[4];
#pragma unroll
  for (int kt = 0; kt < 4; kt++)
    af2[kt] = *reinterpret_cast<const half8v*>(&Z[w * 16 + l16][kt * 32 + quad * 8]);
  __syncthreads();
  floatx4 acc2[4];
#pragma unroll
  for (int ct = 0; ct < 4; ct++) acc2[ct] = {0.f, 0.f, 0.f, 0.f};
#pragma unroll
  for (int kt = 0; kt < 4; kt++) {
#pragma unroll
    for (int ct = 0; ct < 4; ct++) {
      half8v bf = *reinterpret_cast<const half8v*>(&WT1[ct * 16 + l16][kt * 32 + quad * 8]);
      acc2[ct] = __builtin_amdgcn_mfma_f32_16x16x32_f16(af2[kt], bf, acc2[ct], 0, 0, 0);
    }
  }
#pragma unroll
  for (int r = 0; r < 4; r++) {
    long row = rowbase + quad * 4 + r;
    float v[4];
#pragma unroll
    for (int ct = 0; ct < 4; ct++) v[ct] = acc2[ct][r] + ba2[ct * 16 + l16];
    float m = fmaxf(fmaxf(v[0], v[1]), fmaxf(v[2], v[3]));
#pragma unroll
    for (int off = 1; off <= 8; off <<= 1) m = fmaxf(m, __shfl_xor(m, off, 64));
    float se = 0.f;
#pragma unroll
    for (int ct = 0; ct < 4; ct++) { v[ct] = __expf(v[ct] - m); se += v[ct]; }
#pragma unroll
    for (int off = 1; off <= 8; off <<= 1) se += __shfl_xor(se, off, 64);
    float inv = 1.0f / se;
#pragma unroll
    for (int ct = 0; ct < 4; ct++) v[ct] *= inv;
    float m2 = fmaxf(fmaxf(v[0], v[1]), fmaxf(v[2], v[3]));
#pragma unroll
    for (int off = 1; off <= 8; off <<= 1) m2 = fmaxf(m2, __shfl_xor(m2, off, 64));
    float se2 = 0.f;
#pragma unroll
    for (int ct = 0; ct < 4; ct++) { v[ct] = __expf(v[ct] - m2); se2 += v[ct]; }
#pragma unroll
    for (int off = 1; off <= 8; off <<= 1) se2 += __shfl_xor(se2, off, 64);
    float inv2 = 1.0f / se2;
#pragma unroll
    for (int ct = 0; ct < 4; ct++) sh[row * 64 + ct * 16 + l16] = (_Float16)(v[ct] * inv2);
  }
}

// ---------------- GCN aggregation: 16-stride main + one masked 16-tail ----------------
template <int RELU, int DISSRC>
__global__ __launch_bounds__(256) void aggregate_kernel(const _Float16* __restrict__ hs, const float* __restrict__ dis,
                                                        const int* __restrict__ offs, const int* __restrict__ ssrc,
                                                        const float* __restrict__ bias, _Float16* __restrict__ outh) {
  const int lane = threadIdx.x & 63;
  const int b = blockIdx.x;
  const int node = ((b & 7) << 12) + ((b >> 3) << 2) + (threadIdx.x >> 6);
  const int q = lane >> 4;
  const int fl = (lane & 15) * 8;
  const int e0 = offs[node], e1 = offs[node + 1];
  const float dn = dis[node];
  float fa[8];
#pragma unroll
  for (int j = 0; j < 8; j++) fa[j] = 0.f;
  int e = e0;
  for (; e + 16 <= e1; e += 16) {
    int s0 = ssrc[e + q];
    int s1 = ssrc[e + 4 + q];
    int s2 = ssrc[e + 8 + q];
    int s3 = ssrc[e + 12 + q];
    float d0 = 1.f, d1 = 1.f, d2 = 1.f, d3 = 1.f;
    if (DISSRC) { d0 = dis[s0]; d1 = dis[s1]; d2 = dis[s2]; d3 = dis[s3]; }
    half8v v0 = *reinterpret_cast<const half8v*>(hs + (size_t)s0 * 128 + fl);
    half8v v1 = *reinterpret_cast<const half8v*>(hs + (size_t)s1 * 128 + fl);
    half8v v2 = *reinterpret_cast<const half8v*>(hs + (size_t)s2 * 128 + fl);
    half8v v3 = *reinterpret_cast<const half8v*>(hs + (size_t)s3 * 128 + fl);
#pragma unroll
    for (int j = 0; j < 8; j++) {
      if (DISSRC) {
        fa[j] = fmaf(d0, (float)v0[j], fa[j]);
        fa[j] = fmaf(d1, (float)v1[j], fa[j]);
        fa[j] = fmaf(d2, (float)v2[j], fa[j]);
        fa[j] = fmaf(d3, (float)v3[j], fa[j]);
      } else {
        fa[j] += (float)v0[j] + (float)v1[j] + (float)v2[j] + (float)v3[j];
      }
    }
  }
  if (e < e1) {
    int last = e1 - 1;
    int s[4]; bool m[4];
#pragma unroll
    for (int jj = 0; jj < 4; jj++) {
      int idx = e + jj * 4 + q;
      m[jj] = idx < e1;
      int sv = ssrc[idx < last ? idx : last];
      s[jj] = m[jj] ? sv : node;
    }
#pragma unroll
    for (int jj = 0; jj < 4; jj++) {
      half8v v = *reinterpret_cast<const half8v*>(hs + (size_t)s[jj] * 128 + fl);
      float ds = DISSRC ? dis[s[jj]] : 1.f;
      if (m[jj]) {
#pragma unroll
        for (int j = 0; j < 8; j++) {
          if (DISSRC) fa[j] = fmaf(ds, (float)v[j], fa[j]);
          else fa[j] += (float)v[j];
        }
      }
    }
  }
#pragma unroll
  for (int j = 0; j < 8; j++) {
    fa[j] += __shfl_xor(fa[j], 16, 64);
    fa[j] += __shfl_xor(fa[j], 32, 64);
  }
  if (q == 0) {
    half8v self = *reinterpret_cast<const half8v*>(hs + (size_t)node * 128 + fl);
    float4 b0 = *reinterpret_cast<const float4*>(bias + fl);
    float4 b1 = *reinterpret_cast<const float4*>(bias + fl + 4);
    float bb[8] = {b0.x, b0.y, b0.z, b0.w, b1.x, b1.y, b1.z, b1.w};
    half8v r;
#pragma unroll
    for (int j = 0; j < 8; j++) {
      float acc = fa[j];
      if (DISSRC) acc = fmaf(dn, (float)self[j], acc);      // self row unscaled: dis_d * h_d
      else acc += (float)self[j];                            // self row pre-scaled by dis_d
      float v = fmaf(acc, dn, bb[j]);
      if (RELU) v = fmaxf(v, 0.f);
      r[j] = (_Float16)v;
    }
    *reinterpret_cast<half8v*>(outh + (size_t)node * 128 + fl) = r;
  }
}

// ---------------- G + den: 16-stride main + one masked 16-tail ----------------
__global__ __launch_bounds__(256) void gather_kernel(const _Float16* __restrict__ sh, const int* __restrict__ offs,
                                                     const int* __restrict__ ssrc, _Float16* __restrict__ Gh,
                                                     float* __restrict__ dnp) {
  const int lane = threadIdx.x & 63;
  const int b = blockIdx.x;
  const int node = ((b & 7) << 12) + ((b >> 3) << 2) + (threadIdx.x >> 6);
  const int q = lane >> 3;
  const int fl = (lane & 7) * 8;
  const int e0 = offs[node], e1 = offs[node + 1];
  float fa[8];
  float sq = 0.f;
#pragma unroll
  for (int j = 0; j < 8; j++) fa[j] = 0.f;
  int e = e0;
  for (; e + 16 <= e1; e += 16) {
    int s0 = ssrc[e + q];
    int s1 = ssrc[e + 8 + q];
    half8v v0 = *reinterpret_cast<const half8v*>(sh + (size_t)s0 * 64 + fl);
    half8v v1 = *reinterpret_cast<const half8v*>(sh + (size_t)s1 * 64 + fl);
#pragma unroll
    for (int j = 0; j < 8; j++) {
      float f0 = (float)v0[j], f1 = (float)v1[j];
      fa[j] += f0 + f1;
      sq = fmaf(f0, f0, sq);
      sq = fmaf(f1, f1, sq);
    }
  }
  if (e < e1) {
    int last = e1 - 1;
    int i0 = e + q, i1 = e + 8 + q;
    bool m0 = i0 < e1, m1 = i1 < e1;
    int sv0 = ssrc[i0 < last ? i0 : last];
    int sv1 = ssrc[i1 < last ? i1 : last];
    int s0 = m0 ? sv0 : node;
    int s1 = m1 ? sv1 : node;
    half8v v0 = *reinterpret_cast<const half8v*>(sh + (size_t)s0 * 64 + fl);
    half8v v1 = *reinterpret_cast<const half8v*>(sh + (size_t)s1 * 64 + fl);
#pragma unroll
    for (int j = 0; j < 8; j++) {
      float f0 = m0 ? (float)v0[j] : 0.f;
      float f1 = m1 ? (float)v1[j] : 0.f;
      fa[j] += f0 + f1;
      sq = fmaf(f0, f0, sq);
      sq = fmaf(f1, f1, sq);
    }
  }
#pragma unroll
  for (int j = 0; j < 8; j++) {
    fa[j] += __shfl_xor(fa[j], 8, 64);
    fa[j] += __shfl_xor(fa[j], 16, 64);
    fa[j] += __shfl_xor(fa[j], 32, 64);
  }
  float den = wave_sum(sq);
  if (lane == 0) dnp[node] = den;
  if (q == 0) {
    half8v r;
#pragma unroll
    for (int j = 0; j < 8; j++) r[j] = (_Float16)fa[j];
    *reinterpret_cast<half8v*>(Gh + (size_t)node * 64 + fl) = r;
  }
}

// ---------------- rank reduction via MFMA: C[64 x 256] = s_chunk^T [G | s | h2] ----------------
__global__ __launch_bounds__(512) void atb_kernel(const _Float16* __restrict__ sh, const _Float16* __restrict__ Gh,
                                                  const _Float16* __restrict__ h2, float* __restrict__ pF) {
  __shared__ _Float16 XsT[64][136];   // [cluster m][node k 0..127]
  __shared__ _Float16 YsT[256][40];   // [col n][node k 0..31 within kt]
  const int t = threadIdx.x;
  const int g = blockIdx.x & 7, chunk = blockIdx.x >> 3;
  const int n0 = g * 4096 + chunk * 128;
  const int lane = t & 63;
  const int w = t >> 6;
  const int mtile = w & 3;
  const int nhalf = w >> 2;
  const int quad = lane >> 4, l16 = lane & 15;

#pragma unroll
  for (int i = 0; i < 4; i++) {
    int slot = i * 512 + t;
    int k = slot >> 4, c4 = (slot & 15) * 4;
    half4v v = *reinterpret_cast<const half4v*>(&sh[(size_t)(n0 + k) * 64 + c4]);
#pragma unroll
    for (int j = 0; j < 4; j++) XsT[c4 + j][k] = v[j];
  }

  floatx4 acc[8];
#pragma unroll
  for (int nt = 0; nt < 8; nt++) acc[nt] = {0.f, 0.f, 0.f, 0.f};

  for (int kt = 0; kt < 4; ++kt) {
    const int nb = n0 + kt * 32;
    __syncthreads();
#pragma unroll
    for (int i = 0; i < 4; i++) {
      int slot = i * 512 + t;
      int cg = slot & 15, k = (slot >> 4) & 31, ch = slot >> 9;
      int c = ch * 64 + cg * 4;
      half4v v;
      if (c < 64)       v = *reinterpret_cast<const half4v*>(&Gh[(size_t)(nb + k) * 64 + c]);
      else if (c < 128) v = *reinterpret_cast<const half4v*>(&sh[(size_t)(nb + k) * 64 + (c - 64)]);
      else              v = *reinterpret_cast<const half4v*>(&h2[(size_t)(nb + k) * 128 + (c - 128)]);
#pragma unroll
      for (int j = 0; j < 4; j++) YsT[c + j][k] = v[j];
    }
    __syncthreads();
    half8v af = *reinterpret_cast<const half8v*>(&XsT[mtile * 16 + l16][kt * 32 + quad * 8]);
#pragma unroll
    for (int nt = 0; nt < 8; nt++) {
      half8v bf = *reinterpret_cast<const half8v*>(&YsT[(nhalf * 8 + nt) * 16 + l16][quad * 8]);
      acc[nt] = __builtin_amdgcn_mfma_f32_16x16x32_f16(af, bf, acc[nt], 0, 0, 0);
    }
  }
  float* dst = pF + (size_t)blockIdx.x * 16384;
#pragma unroll
  for (int nt = 0; nt < 8; nt++) {
#pragma unroll
    for (int r = 0; r < 4; r++) {
      dst[(mtile * 16 + quad * 4 + r) * 256 + (nhalf * 8 + nt) * 16 + l16] = acc[nt][r];
    }
  }
}

// ---------------- merge 32 partials/graph -> oadj, ssb, outp16 ----------------
__global__ __launch_bounds__(256) void merge_kernel(const float* __restrict__ pF, float* __restrict__ oadj,
                                                    float* __restrict__ ssb, _Float16* __restrict__ outp16) {
  int g = blockIdx.x & 7;
  int o4 = (blockIdx.x >> 3) * 256 + threadIdx.x;
  float sx = 0.f, sy = 0.f, sz = 0.f, sw = 0.f;
#pragma unroll
  for (int q = 0; q < 32; ++q) {
    float4 v = *reinterpret_cast<const float4*>(pF + (size_t)(q * 8 + g) * 16384 + o4 * 4);
    sx += v.x; sy += v.y; sz += v.z; sw += v.w;
  }
  int row = o4 >> 6;
  int c = (o4 & 63) * 4;
  if (c < 64) {
    float4 o = {sx, sy, sz, sw};
    *reinterpret_cast<float4*>(&oadj[g * 4096 + row * 64 + c]) = o;
  } else if (c < 128) {
    float4 o = {sx, sy, sz, sw};
    *reinterpret_cast<float4*>(&ssb[g * 4096 + row * 64 + (c - 64)]) = o;
  } else {
    half4v h = {(_Float16)sx, (_Float16)sy, (_Float16)sz, (_Float16)sw};
    *reinterpret_cast<half4v*>(&outp16[g * 8192 + row * 128 + (c - 128)]) = h;
  }
}

// ---------------- epilogue2: losses + adj-norm + pooled MFMA GEMM (8 blocks) ----------------
__global__ __launch_bounds__(256) void epilogue2_kernel(const float* __restrict__ oadj, const float* __restrict__ ssb,
                                                        const _Float16* __restrict__ outp16, const _Float16* __restrict__ wto,
                                                        const float* __restrict__ bo, const float* __restrict__ dn,
                                                        float* __restrict__ out) {
  __shared__ _Float16 outpS[64][136];
  __shared__ _Float16 WoT[128][136];
  __shared__ float red[256];
  __shared__ float rowsum[64];
  __shared__ float dw[4], w1[4], w2[4], w3[4];
  const int g = blockIdx.x, t = threadIdx.x;

#pragma unroll
  for (int i = 0; i < 8; i++) {
    int idx = i * 256 + t;
    int n = idx >> 4, k8 = (idx & 15) << 3;
    *reinterpret_cast<half8v*>(&WoT[n][k8]) = *reinterpret_cast<const half8v*>(&wto[n * 128 + k8]);
  }
#pragma unroll
  for (int i = 0; i < 4; i++) {
    int idx = i * 256 + t;
    int orow = idx >> 4, c8 = (idx & 15) * 8;
    half8v v = *reinterpret_cast<const half8v*>(&outp16[g * 8192 + orow * 128 + c8]);
    *reinterpret_cast<half8v*>(&outpS[orow][c8]) = v;
  }

  const int row = t >> 2, p = t & 3;
  float Areg[16];
  float trs_p = 0.f, ssq_p = 0.f;
#pragma unroll
  for (int c4 = 0; c4 < 4; c4++) {
    float4 a = *reinterpret_cast<const float4*>(&oadj[g * 4096 + row * 64 + p * 16 + c4 * 4]);
    Areg[c4 * 4 + 0] = a.x; Areg[c4 * 4 + 1] = a.y; Areg[c4 * 4 + 2] = a.z; Areg[c4 * 4 + 3] = a.w;
    float4 s = *reinterpret_cast<const float4*>(&ssb[g * 4096 + row * 64 + p * 16 + c4 * 4]);
    float vv[4] = {s.x, s.y, s.z, s.w};
#pragma unroll
    for (int jj = 0; jj < 4; jj++) {
      ssq_p += vv[jj] * vv[jj];
      int col = p * 16 + c4 * 4 + jj;
      if (col == row) trs_p += vv[jj];
    }
  }
  float da = 0.f;
#pragma unroll
  for (int i = 0; i < 16; i++) da += dn[g * 4096 + i * 256 + t];
  float dws = wave_sum(da);
  if ((t & 63) == 0) dw[t >> 6] = dws;

  float rs = 0.f, tra = 0.f;
#pragma unroll
  for (int c = 0; c < 16; c++) {
    int j = p * 16 + c;
    if (j == row) tra += Areg[c];
    else rs += Areg[c];
  }
  red[t] = rs;
  __syncthreads();
  if (p == 0) rowsum[row] = red[t] + red[t + 1] + red[t + 2] + red[t + 3];
  float v1 = wave_sum(tra), v2 = wave_sum(trs_p), v3 = wave_sum(ssq_p);
  if ((t & 63) == 0) { int w = t >> 6; w1[w] = v1; w2[w] = v2; w3[w] = v3; }
  __syncthreads();
  if (t == 0) {
    float TRA = w1[0] + w1[1] + w1[2] + w1[3];
    float TRS = w2[0] + w2[1] + w2[2] + w2[3];
    float SSQ = w3[0] + w3[1] + w3[2] + w3[3];
    float DEN = dw[0] + dw[1] + dw[2] + dw[3];
    atomicAdd(&out[98816], -(TRA / DEN) * 0.125f);
    float ssn = sqrtf(SSQ);
    atomicAdd(&out[98817], sqrtf(2.0f - TRS / (4.0f * ssn)) * 0.125f);
  }
  float di = sqrtf(rowsum[row]) + 1e-15f;
#pragma unroll
  for (int c = 0; c < 16; c++) {
    int j = p * 16 + c;
    float v = (j == row) ? 0.f : Areg[c];
    float dj = sqrtf(rowsum[j]) + 1e-15f;
    out[65536 + g * 4096 + row * 64 + j] = v / (di * dj);
  }
  if (t < 64) out[98304 + g * 64 + t] = (float)g;

  const int lane = t & 63;
  const int quad = lane >> 4, l16 = lane & 15;
  const int w = t >> 6;
  floatx4 acc[8];
#pragma unroll
  for (int ct = 0; ct < 8; ct++) acc[ct] = {0.f, 0.f, 0.f, 0.f};
#pragma unroll
  for (int kt = 0; kt < 4; kt++) {
    half8v af = *reinterpret_cast<const half8v*>(&outpS[w * 16 + l16][kt * 32 + quad * 8]);
#pragma unroll
    for (int ct = 0; ct < 8; ct++) {
      half8v bf = *reinterpret_cast<const half8v*>(&WoT[ct * 16 + l16][kt * 32 + quad * 8]);
      acc[ct] = __builtin_amdgcn_mfma_f32_16x16x32_f16(af, bf, acc[ct], 0, 0, 0);
    }
  }
#pragma unroll
  for (int r = 0; r < 4; r++) {
    int orow = w * 16 + quad * 4 + r;
#pragma unroll
    for (int ct = 0; ct < 8; ct++) {
      int col = ct * 16 + l16;
      float v = fmaxf(acc[ct][r] + bo[col], 0.f);
      out[(g * 64 + orow) * 128 + col] = v;
    }
  }
}

extern "C" void kernel_launch(void* const* d_in, const int* in_sizes, int n_in,
                              void* d_out, int out_size, void* d_ws, size_t ws_size,
                              hipStream_t stream) {
  const float* x   = (const float*)d_in[0];
  const int*   ei  = (const int*)d_in[1];
  const float* W1  = (const float*)d_in[3];
  const float* b1  = (const float*)d_in[4];
  const float* W2  = (const float*)d_in[5];
  const float* b2  = (const float*)d_in[6];
  const float* Wa1 = (const float*)d_in[7];
  const float* ba1 = (const float*)d_in[8];
  const float* Wa2 = (const float*)d_in[9];
  const float* ba2 = (const float*)d_in[10];
  const float* Wo  = (const float*)d_in[11];
  const float* bo  = (const float*)d_in[12];
  const int* src = ei;
  const int* dst = ei + NEDGES;
  float* out = (float*)d_out;

  char* ws = (char*)d_ws;
  size_t o = 0;
  auto alloc = [&](size_t bytes) -> void* {
    void* p = ws + o;
    o += (bytes + 255) & ~(size_t)255;
    return p;
  };
  _Float16* h16A = (_Float16*)alloc((size_t)NNODES * 128 * 2);
  _Float16* h16B = (_Float16*)alloc((size_t)NNODES * 128 * 2);
  _Float16* h16C = (_Float16*)alloc((size_t)NNODES * 128 * 2);
  _Float16* sh   = (_Float16*)alloc((size_t)NNODES * 64 * 2);
  _Float16* Gh   = (_Float16*)alloc((size_t)NNODES * 64 * 2);
  float* pF    = (float*)alloc((size_t)256 * 16384 * 4);
  float* dis   = (float*)alloc((size_t)NNODES * 4);
  int* offs    = (int*)alloc((size_t)(NNODES + 1) * 4);
  int* ssrc    = (int*)alloc((size_t)NEDGES * 4);
  int* pIn     = (int*)alloc((size_t)8 * CPG * 4096 * 4);
  int* cbase   = (int*)alloc((size_t)8 * CPG * 4096 * 4);
  float* dn    = (float*)alloc((size_t)NNODES * 4);
  float* oadj  = (float*)alloc(8 * 4096 * 4);
  float* ssb   = (float*)alloc(8 * 4096 * 4);
  _Float16* outp16 = (_Float16*)alloc(8 * 8192 * 2);
  _Float16* wt16   = (_Float16*)alloc((size_t)WT_TOTAL * 2);

  // 1: histogram (blocks 0..127) || layer-1 GEMM (blocks 128..383, unscaled)
  histgemm1_kernel<<<384, 256, 0, stream>>>(src, dst, pIn, W1, W2, Wa1, Wa2, Wo, wt16, x, h16A, out);
  // 2-3: CSR build (shuffle-scan: 1 barrier; LDS-cursor scatter with int4 staging)
  scan2_kernel<<<8, 1024, 0, stream>>>(pIn, offs, cbase, dis);
  scatter2_kernel<<<8 * CPG, 256, 0, stream>>>(src, dst, cbase, ssrc);

  // layer 1 aggregate: per-edge dis[src] (deferred producer scale) + dis[dst], bias, relu
  aggregate_kernel<1, 1><<<NNODES / 4, 256, 0, stream>>>(h16A, dis, offs, ssrc, b1, h16B);
  mgemm_kernel<0, 0, 1, 0><<<NNODES / 128, 256, 0, stream>>>(h16B, wt16 + WT2_OFF, nullptr, dis, h16A);
  aggregate_kernel<0, 0><<<NNODES / 4, 256, 0, stream>>>(h16A, dis, offs, ssrc, b2, h16C);

  mlp_kernel<<<NNODES / 64, 256, 0, stream>>>(h16C, wt16 + WTA1_OFF, wt16 + WTA2_OFF, ba1, ba2, sh);

  gather_kernel<<<NNODES / 4, 256, 0, stream>>>(sh, offs, ssrc, Gh, dn);
  atb_kernel<<<256, 512, 0, stream>>>(sh, Gh, h16C, pF);
  merge_kernel<<<128, 256, 0, stream>>>(pF, oadj, ssb, outp16);
  epilogue2_kernel<<<8, 256, 0, stream>>>(oadj, ssb, outp16, wt16 + WTO_OFF, bo, dn, out);
}